// Round 1
// baseline (3727.575 us; speedup 1.0000x reference)
//
#include <hip/hip_runtime.h>

#define Hc 96
#define Wc 96
#define Cc 256
#define Bc 4
#define KK 9
#define HW 9216          // Hc*Wc
#define PIX 36864        // Bc*HW
#define CK 2304          // Cc*KK

__device__ __forceinline__ int clampi(int v, int lo, int hi) {
    return v < lo ? lo : (v > hi ? hi : v);
}

// wT[ck*256 + o] = w[(o*Cc + c)*9 + k],  ck = c*9 + k
__global__ __launch_bounds__(256) void transpose_w_kernel(
    const float* __restrict__ w, float* __restrict__ wT)
{
    int t = blockIdx.x * 256 + threadIdx.x;   // t < CK*Cc = 589824
    int o = t & 255, ck = t >> 8;
    wT[t] = w[o * CK + ck];
}

// Offset conv, channel-chunked: partial[(cch*18 + j)*PIX + t]
__global__ __launch_bounds__(256) void conv_off_partial_kernel(
    const float* __restrict__ x, const float* __restrict__ w_off,
    float* __restrict__ part)
{
    int t = blockIdx.x * 256 + threadIdx.x;   // pixel
    int cch = blockIdx.y;                     // 0..3, 64 channels each
    int b = t / HW, hw = t - b * HW;
    int h = hw / Wc, wc = hw - h * Wc;
    float acc[18];
#pragma unroll
    for (int j = 0; j < 18; ++j) acc[j] = 0.f;
    const float* xb = x + (size_t)(b * Cc + cch * 64) * HW;
    for (int c = 0; c < 64; ++c) {
        const float* xp = xb + (size_t)c * HW;
        const float* wo = w_off + (size_t)(cch * 64 + c) * 9;
#pragma unroll
        for (int dy = 0; dy < 3; ++dy) {
            int yy = h + dy - 1;
            if (yy < 0 || yy >= Hc) continue;
#pragma unroll
            for (int dx = 0; dx < 3; ++dx) {
                int xx = wc + dx - 1;
                if (xx < 0 || xx >= Wc) continue;
                float xv = xp[yy * Wc + xx];
#pragma unroll
                for (int j = 0; j < 18; ++j)
                    acc[j] = fmaf(xv, wo[j * Cc * 9 + dy * 3 + dx], acc[j]);
            }
        }
    }
#pragma unroll
    for (int j = 0; j < 18; ++j)
        part[(size_t)(cch * 18 + j) * PIX + t] = acc[j];
}

// Sum partials + bias, compute bilinear gather indices/weights per sample pt
__global__ __launch_bounds__(256) void off_reduce_kernel(
    const float* __restrict__ part, const float* __restrict__ b_off,
    int4* __restrict__ idx4, float4* __restrict__ wt4)
{
    int t = blockIdx.x * 256 + threadIdx.x;   // pixel
    int b = t / HW, hw = t - b * HW;
    int h = hw / Wc, wc = hw - h * Wc;
    (void)b;
    float off[18];
#pragma unroll
    for (int j = 0; j < 18; ++j)
        off[j] = b_off[j]
               + part[(size_t)(0 * 18 + j) * PIX + t]
               + part[(size_t)(1 * 18 + j) * PIX + t]
               + part[(size_t)(2 * 18 + j) * PIX + t]
               + part[(size_t)(3 * 18 + j) * PIX + t];
#pragma unroll
    for (int k = 0; k < KK; ++k) {
        float py = (float)(h - 1 + k / 3) + off[2 * k];
        float px = (float)(wc - 1 + k % 3) + off[2 * k + 1];
        float y0f = floorf(py), x0f = floorf(px);
        float wy = py - y0f, wx = px - x0f;
        int iy0 = (int)y0f, ix0 = (int)x0f;
        float vy0 = (y0f >= 0.f && y0f <= (float)(Hc - 1)) ? 1.f : 0.f;
        float vy1 = (y0f + 1.f >= 0.f && y0f + 1.f <= (float)(Hc - 1)) ? 1.f : 0.f;
        float vx0 = (x0f >= 0.f && x0f <= (float)(Wc - 1)) ? 1.f : 0.f;
        float vx1 = (x0f + 1.f >= 0.f && x0f + 1.f <= (float)(Wc - 1)) ? 1.f : 0.f;
        int cy0 = clampi(iy0, 0, Hc - 1), cy1 = clampi(iy0 + 1, 0, Hc - 1);
        int cx0 = clampi(ix0, 0, Wc - 1), cx1 = clampi(ix0 + 1, 0, Wc - 1);
        idx4[(size_t)t * KK + k] = make_int4(cy0 * Wc + cx0, cy0 * Wc + cx1,
                                             cy1 * Wc + cx0, cy1 * Wc + cx1);
        wt4[(size_t)t * KK + k] = make_float4((1.f - wy) * (1.f - wx) * vy0 * vx0,
                                              (1.f - wy) * wx * vy0 * vx1,
                                              wy * (1.f - wx) * vy1 * vx0,
                                              wy * wx * vy1 * vx1);
    }
}

// Fused deformable sampling + GEMM + ReLU.
// Block: 64 pixels (M) x 256 outputs (N); K loop over c (x9 taps).
__global__ __launch_bounds__(256) void deform_gemm_kernel(
    const float* __restrict__ x, const float* __restrict__ wT,
    const int4* __restrict__ idx4, const float4* __restrict__ wt4,
    float* __restrict__ out)
{
    __shared__ int4   s_idx[576];   // [k*64 + p]
    __shared__ float4 s_wt [576];   // [k*64 + p]
    __shared__ int    s_pb [64];    // plane base: b*Cc*HW per pixel
    __shared__ float  s_samp[576];  // [k*64 + p]
    __shared__ float  s_w  [2304];  // [k*256 + o]

    const int tid = threadIdx.x;
    const int p0 = blockIdx.x * 64;
    const int tx = tid & 15, ty = tid >> 4;

    for (int s = tid; s < 576; s += 256) {
        int pp = s / 9, kk = s - pp * 9;
        s_idx[kk * 64 + pp] = idx4[(size_t)p0 * KK + s];
        s_wt [kk * 64 + pp] = wt4 [(size_t)p0 * KK + s];
    }
    if (tid < 64) s_pb[tid] = ((p0 + tid) / HW) * (Cc * HW);

    float acc[4][16];
#pragma unroll
    for (int i = 0; i < 4; ++i)
#pragma unroll
        for (int j = 0; j < 16; ++j) acc[i][j] = 0.f;

    __syncthreads();

    for (int c = 0; c < Cc; ++c) {
        // stage weights for this channel: coalesced from wT
#pragma unroll
        for (int t = tid; t < 2304; t += 256)
            s_w[t] = wT[(size_t)c * CK + t];
        // stage sampled values: 576 = 9 taps x 64 pixels
        for (int s = tid; s < 576; s += 256) {
            int pp = s & 63;
            int4   id = s_idx[s];
            float4 wv = s_wt[s];
            const float* xc = x + s_pb[pp] + (size_t)c * HW;
            s_samp[s] = wv.x * xc[id.x] + wv.y * xc[id.y] +
                        wv.z * xc[id.z] + wv.w * xc[id.w];
        }
        __syncthreads();
#pragma unroll
        for (int k = 0; k < KK; ++k) {
            float4 sv = *(const float4*)&s_samp[k * 64 + ty * 4];
            float sa[4] = {sv.x, sv.y, sv.z, sv.w};
#pragma unroll
            for (int q = 0; q < 4; ++q) {
                float4 wv = *(const float4*)&s_w[k * 256 + q * 64 + tx * 4];
                float wa[4] = {wv.x, wv.y, wv.z, wv.w};
#pragma unroll
                for (int i = 0; i < 4; ++i)
#pragma unroll
                    for (int e = 0; e < 4; ++e)
                        acc[i][q * 4 + e] = fmaf(sa[i], wa[e], acc[i][q * 4 + e]);
            }
        }
        __syncthreads();
    }

    // epilogue: relu + store, 4 contiguous pixels per float4
    int gp0 = p0 + ty * 4;
    int gb = gp0 / HW;
    int hw0 = gp0 - gb * HW;
    float* ob = out + (size_t)gb * Cc * HW + hw0;
#pragma unroll
    for (int q = 0; q < 4; ++q)
#pragma unroll
        for (int e = 0; e < 4; ++e) {
            int o = q * 64 + tx * 4 + e;
            int j = q * 4 + e;
            float4 v;
            v.x = fmaxf(acc[0][j], 0.f);
            v.y = fmaxf(acc[1][j], 0.f);
            v.z = fmaxf(acc[2][j], 0.f);
            v.w = fmaxf(acc[3][j], 0.f);
            *(float4*)(ob + (size_t)o * HW) = v;
        }
}

extern "C" void kernel_launch(void* const* d_in, const int* in_sizes, int n_in,
                              void* d_out, int out_size, void* d_ws, size_t ws_size,
                              hipStream_t stream)
{
    const float* x0 = (const float*)d_in[0];
    float* out = (float*)d_out;
    float* ws = (float*)d_ws;

    float* buf0 = ws;                                  // PIX*Cc floats
    float* buf1 = buf0 + (size_t)PIX * Cc;             // PIX*Cc floats
    float* wT   = buf1 + (size_t)PIX * Cc;             // CK*Cc floats
    float* part = wT + (size_t)CK * Cc;                // 72*PIX floats
    int4*  idx4 = (int4*)(part + (size_t)72 * PIX);    // PIX*KK int4
    float4* wt4 = (float4*)(idx4 + (size_t)PIX * KK);  // PIX*KK float4

    const float* xin = x0;
    for (int L = 0; L < 3; ++L) {
        const float* w_off = (const float*)d_in[1 + 3 * L];
        const float* b_off = (const float*)d_in[2 + 3 * L];
        const float* w     = (const float*)d_in[3 + 3 * L];
        float* xout = (L == 0) ? buf0 : (L == 1) ? buf1 : out;

        transpose_w_kernel<<<(CK * Cc) / 256, 256, 0, stream>>>(w, wT);
        conv_off_partial_kernel<<<dim3(PIX / 256, 4), 256, 0, stream>>>(xin, w_off, part);
        off_reduce_kernel<<<PIX / 256, 256, 0, stream>>>(part, b_off, idx4, wt4);
        deform_gemm_kernel<<<PIX / 64, 256, 0, stream>>>(xin, wT, idx4, wt4, xout);

        xin = xout;
    }
}

// Round 2
// 1753.104 us; speedup vs baseline: 2.1263x; 2.1263x over previous
//
#include <hip/hip_runtime.h>

#define Hc 96
#define Wc 96
#define Cc 256
#define Bc 4
#define KK 9
#define HW 9216          // Hc*Wc
#define PIX 36864        // Bc*HW
#define CK 2304          // Cc*KK

typedef _Float16 f16;
typedef __attribute__((ext_vector_type(8))) _Float16 f16x8;
typedef __attribute__((ext_vector_type(4))) float f32x4;

__device__ __forceinline__ int clampi(int v, int lo, int hi) {
    return v < lo ? lo : (v > hi ? hi : v);
}

// wT2[(k*256 + o)*256 + c] = (f16) w[(o*256 + c)*9 + k]
__global__ __launch_bounds__(256) void transpose_w_kernel(
    const float* __restrict__ w, f16* __restrict__ wT2)
{
    int u = blockIdx.x * 256 + threadIdx.x;   // < 589824
    int c = u & 255, o = (u >> 8) & 255, k = u >> 16;
    wT2[u] = (f16)w[(o * Cc + c) * KK + k];
}

// Offset conv, channel-chunked: partial[(cch*18 + j)*PIX + t]
__global__ __launch_bounds__(256) void conv_off_partial_kernel(
    const float* __restrict__ x, const float* __restrict__ w_off,
    float* __restrict__ part)
{
    int t = blockIdx.x * 256 + threadIdx.x;   // pixel
    int cch = blockIdx.y;                     // 0..3, 64 channels each
    int b = t / HW, hw = t - b * HW;
    int h = hw / Wc, wc = hw - h * Wc;
    float acc[18];
#pragma unroll
    for (int j = 0; j < 18; ++j) acc[j] = 0.f;
    const float* xb = x + (size_t)(b * Cc + cch * 64) * HW;
    for (int c = 0; c < 64; ++c) {
        const float* xp = xb + (size_t)c * HW;
        const float* wo = w_off + (size_t)(cch * 64 + c) * 9;
#pragma unroll
        for (int dy = 0; dy < 3; ++dy) {
            int yy = h + dy - 1;
            if (yy < 0 || yy >= Hc) continue;
#pragma unroll
            for (int dx = 0; dx < 3; ++dx) {
                int xx = wc + dx - 1;
                if (xx < 0 || xx >= Wc) continue;
                float xv = xp[yy * Wc + xx];
#pragma unroll
                for (int j = 0; j < 18; ++j)
                    acc[j] = fmaf(xv, wo[j * Cc * 9 + dy * 3 + dx], acc[j]);
            }
        }
    }
#pragma unroll
    for (int j = 0; j < 18; ++j)
        part[(size_t)(cch * 18 + j) * PIX + t] = acc[j];
}

// Sum partials + bias, compute bilinear gather indices/weights per sample pt
__global__ __launch_bounds__(256) void off_reduce_kernel(
    const float* __restrict__ part, const float* __restrict__ b_off,
    int4* __restrict__ idx4, float4* __restrict__ wt4)
{
    int t = blockIdx.x * 256 + threadIdx.x;   // pixel
    int b = t / HW, hw = t - b * HW;
    int h = hw / Wc, wc = hw - h * Wc;
    (void)b;
    float off[18];
#pragma unroll
    for (int j = 0; j < 18; ++j)
        off[j] = b_off[j]
               + part[(size_t)(0 * 18 + j) * PIX + t]
               + part[(size_t)(1 * 18 + j) * PIX + t]
               + part[(size_t)(2 * 18 + j) * PIX + t]
               + part[(size_t)(3 * 18 + j) * PIX + t];
#pragma unroll
    for (int k = 0; k < KK; ++k) {
        float py = (float)(h - 1 + k / 3) + off[2 * k];
        float px = (float)(wc - 1 + k % 3) + off[2 * k + 1];
        float y0f = floorf(py), x0f = floorf(px);
        float wy = py - y0f, wx = px - x0f;
        int iy0 = (int)y0f, ix0 = (int)x0f;
        float vy0 = (y0f >= 0.f && y0f <= (float)(Hc - 1)) ? 1.f : 0.f;
        float vy1 = (y0f + 1.f >= 0.f && y0f + 1.f <= (float)(Hc - 1)) ? 1.f : 0.f;
        float vx0 = (x0f >= 0.f && x0f <= (float)(Wc - 1)) ? 1.f : 0.f;
        float vx1 = (x0f + 1.f >= 0.f && x0f + 1.f <= (float)(Wc - 1)) ? 1.f : 0.f;
        int cy0 = clampi(iy0, 0, Hc - 1), cy1 = clampi(iy0 + 1, 0, Hc - 1);
        int cx0 = clampi(ix0, 0, Wc - 1), cx1 = clampi(ix0 + 1, 0, Wc - 1);
        idx4[(size_t)t * KK + k] = make_int4(cy0 * Wc + cx0, cy0 * Wc + cx1,
                                             cy1 * Wc + cx0, cy1 * Wc + cx1);
        wt4[(size_t)t * KK + k] = make_float4((1.f - wy) * (1.f - wx) * vy0 * vx0,
                                              (1.f - wy) * wx * vy0 * vx1,
                                              wy * (1.f - wx) * vy1 * vx0,
                                              wy * wx * vy1 * vx1);
    }
}

// Fused deformable sampling + f16-MFMA GEMM + ReLU.
// Block: 256 outputs (M of MFMA) x 64 pixels (N of MFMA). 4 waves,
// wave wid owns outputs [wid*64, wid*64+64) x all 64 pixels.
// K loop: tap k (9) x channel chunk (8 x 32).
__global__ __launch_bounds__(256) void deform_mfma_kernel(
    const float* __restrict__ x, const f16* __restrict__ wT2,
    const int4* __restrict__ idx4, const float4* __restrict__ wt4,
    float* __restrict__ out)
{
    __shared__ int4   s_idx[576];              // [k][m]  9KB
    __shared__ float4 s_wt [576];              // [k][m]  9KB
    __shared__ __align__(16) f16 s_w[256 * 32]; // [o][kk] swizzled, 16KB
    __shared__ __align__(16) f16 s_s[64 * 32];  // [pix][kk] swizzled, 4KB

    const int tid = threadIdx.x;
    const int lane = tid & 63;
    const int wid = tid >> 6;
    const int p0 = blockIdx.x * 64;
    const int pb = (p0 / HW) * (Cc * HW);      // image base (block-uniform)

    for (int s = tid; s < 576; s += 256) {
        int pp = s / 9, kk = s - pp * 9;
        s_idx[kk * 64 + pp] = idx4[(size_t)p0 * KK + s];
        s_wt [kk * 64 + pp] = wt4 [(size_t)p0 * KK + s];
    }

    f32x4 acc[4][4];
#pragma unroll
    for (int mi = 0; mi < 4; ++mi)
#pragma unroll
        for (int ni = 0; ni < 4; ++ni)
            acc[mi][ni] = (f32x4){0.f, 0.f, 0.f, 0.f};

    // lane-constant swizzle terms
    const int qa = ((lane >> 4) ^ ((lane >> 1) & 3)) * 8; // frag-read elem off
    const int qg = ((lane & 3) ^ ((lane >> 3) & 3)) * 8;  // pre-swizzled global
    const int qs = (wid ^ ((lane >> 1) & 3)) * 8;         // sample ds_write

    __syncthreads();

    for (int k = 0; k < 9; ++k) {
        const int4   id = s_idx[k * 64 + lane];
        const float4 wv = s_wt[k * 64 + lane];
        for (int ch = 0; ch < 8; ++ch) {
            const int c0 = ch * 32;
            // stage weights: 16 x 1KB wave-chunks, pre-swizzled global source
#pragma unroll
            for (int it = 0; it < 4; ++it) {
                int chunk = wid * 4 + it;
                int n = chunk * 16 + (lane >> 2);
                const f16* gsrc = wT2 + ((size_t)(k * 256 + n) * 256 + c0) + qg;
                __builtin_amdgcn_global_load_lds(
                    (const __attribute__((address_space(1))) void*)gsrc,
                    (__attribute__((address_space(3))) void*)&s_w[chunk * 512],
                    16, 0, 0);
            }
            // sample 8 channels for pixel `lane`, tap k
            const float* xc = x + pb + (size_t)(c0 + wid * 8) * HW;
            f16x8 vals;
#pragma unroll
            for (int j = 0; j < 8; ++j) {
                float sv = wv.x * xc[id.x] + wv.y * xc[id.y] +
                           wv.z * xc[id.z] + wv.w * xc[id.w];
                vals[j] = (f16)sv;
                xc += HW;
            }
            *(f16x8*)&s_s[lane * 32 + qs] = vals;
            __syncthreads();

            // fragments + 16 MFMAs
            f16x8 a[4];
#pragma unroll
            for (int mi = 0; mi < 4; ++mi)
                a[mi] = *(const f16x8*)&s_w[(wid * 64 + mi * 16 + (lane & 15)) * 32 + qa];
#pragma unroll
            for (int ni = 0; ni < 4; ++ni) {
                f16x8 b = *(const f16x8*)&s_s[(ni * 16 + (lane & 15)) * 32 + qa];
#pragma unroll
                for (int mi = 0; mi < 4; ++mi)
                    acc[mi][ni] = __builtin_amdgcn_mfma_f32_16x16x32_f16(
                        a[mi], b, acc[mi][ni], 0, 0, 0);
            }
            __syncthreads();
        }
    }

    // epilogue: ReLU + store. D: row(=output)=(lane>>4)*4+j, col(=pixel)=lane&15
    const int hw0 = p0 - (p0 / HW) * HW;
#pragma unroll
    for (int mi = 0; mi < 4; ++mi) {
#pragma unroll
        for (int ni = 0; ni < 4; ++ni) {
#pragma unroll
            for (int j = 0; j < 4; ++j) {
                int o = wid * 64 + mi * 16 + (lane >> 4) * 4 + j;
                int hw = hw0 + ni * 16 + (lane & 15);
                out[(size_t)pb + (size_t)o * HW + hw] = fmaxf(acc[mi][ni][j], 0.f);
            }
        }
    }
}

extern "C" void kernel_launch(void* const* d_in, const int* in_sizes, int n_in,
                              void* d_out, int out_size, void* d_ws, size_t ws_size,
                              hipStream_t stream)
{
    const float* x0 = (const float*)d_in[0];
    float* out = (float*)d_out;
    float* ws = (float*)d_ws;

    float* buf0 = ws;                                  // PIX*Cc floats
    float* buf1 = buf0 + (size_t)PIX * Cc;             // PIX*Cc floats
    f16*   wT2  = (f16*)(buf1 + (size_t)PIX * Cc);     // CK*Cc f16
    float* part = (float*)(wT2 + (size_t)CK * Cc);     // 72*PIX floats
    int4*  idx4 = (int4*)(part + (size_t)72 * PIX);    // PIX*KK int4
    float4* wt4 = (float4*)(idx4 + (size_t)PIX * KK);  // PIX*KK float4

    const float* xin = x0;
    for (int L = 0; L < 3; ++L) {
        const float* w_off = (const float*)d_in[1 + 3 * L];
        const float* b_off = (const float*)d_in[2 + 3 * L];
        const float* w     = (const float*)d_in[3 + 3 * L];
        float* xout = (L == 0) ? buf0 : (L == 1) ? buf1 : out;

        transpose_w_kernel<<<(CK * Cc) / 256, 256, 0, stream>>>(w, wT2);
        conv_off_partial_kernel<<<dim3(PIX / 256, 4), 256, 0, stream>>>(xin, w_off, part);
        off_reduce_kernel<<<PIX / 256, 256, 0, stream>>>(part, b_off, idx4, wt4);
        deform_mfma_kernel<<<PIX / 64, 256, 0, stream>>>(xin, wT2, idx4, wt4, xout);

        xin = xout;
    }
}

// Round 3
// 1284.487 us; speedup vs baseline: 2.9020x; 1.3648x over previous
//
#include <hip/hip_runtime.h>

#define Hc 96
#define Wc 96
#define Cc 256
#define Bc 4
#define KK 9
#define HW 9216          // Hc*Wc
#define PIX 36864        // Bc*HW
#define CK 2304          // Cc*KK

typedef _Float16 f16;
typedef __attribute__((ext_vector_type(4))) _Float16 f16x4;
typedef __attribute__((ext_vector_type(8))) _Float16 f16x8;
typedef __attribute__((ext_vector_type(4))) float f32x4;

__device__ __forceinline__ int clampi(int v, int lo, int hi) {
    return v < lo ? lo : (v > hi ? hi : v);
}

// ---------- prep: NCHW fp32 -> NHWC fp32 + NHWC f16 (layer 0 input) ----------
__global__ __launch_bounds__(256) void nhwc_prep_kernel(
    const float* __restrict__ x0, float* __restrict__ x32, f16* __restrict__ x16)
{
    __shared__ float st[64][65];
    const int hw0 = blockIdx.x * 64;
    const int c0  = blockIdx.y * 64;
    const int b   = blockIdx.z;
    const int tid = threadIdx.x;
    const int a = tid & 63, r = tid >> 6;
#pragma unroll
    for (int it = 0; it < 16; ++it) {
        int cl = it * 4 + r;
        st[cl][a] = x0[((size_t)(b * Cc + c0 + cl)) * HW + hw0 + a];
    }
    __syncthreads();
#pragma unroll
    for (int it = 0; it < 16; ++it) {
        int hwl = it * 4 + r;
        float v = st[a][hwl];
        size_t p = ((size_t)(b * HW + hw0 + hwl)) * Cc + c0 + a;
        x32[p] = v;
        x16[p] = (f16)v;
    }
}

// wT2[(k*256 + o)*256 + c] = (f16) w[(o*256 + c)*9 + k]
__global__ __launch_bounds__(256) void transpose_w_kernel(
    const float* __restrict__ w, f16* __restrict__ wT2)
{
    int u = blockIdx.x * 256 + threadIdx.x;   // < 589824
    int c = u & 255, o = (u >> 8) & 255, k = u >> 16;
    wT2[u] = (f16)w[(o * Cc + c) * KK + k];
}

// woffT[(k*32 + j)*256 + c] = (f16) w_off[(j*256 + c)*9 + k], rows 18..31 = 0
__global__ __launch_bounds__(256) void woff_prep_kernel(
    const float* __restrict__ w_off, f16* __restrict__ woffT)
{
    int u = blockIdx.x * 256 + threadIdx.x;   // < 73728
    int c = u & 255, j = (u >> 8) & 31, k = u >> 13;
    float v = (j < 18) ? w_off[((size_t)j * Cc + c) * KK + k] : 0.f;
    woffT[u] = (f16)v;
}

// bilinear decomposition for one tap -> idx4/wt4 (tap-major layout)
__device__ __forceinline__ void store_tap(int k, int h, int w, float offy, float offx,
    int p, int4* __restrict__ idx4t, float4* __restrict__ wt4t)
{
    float py = (float)(h - 1 + k / 3) + offy;
    float px = (float)(w - 1 + k % 3) + offx;
    float y0f = floorf(py), x0f = floorf(px);
    float wy = py - y0f, wx = px - x0f;
    int iy0 = (int)y0f, ix0 = (int)x0f;
    float vy0 = (y0f >= 0.f && y0f <= 95.f) ? 1.f : 0.f;
    float vy1 = (y0f + 1.f >= 0.f && y0f + 1.f <= 95.f) ? 1.f : 0.f;
    float vx0 = (x0f >= 0.f && x0f <= 95.f) ? 1.f : 0.f;
    float vx1 = (x0f + 1.f >= 0.f && x0f + 1.f <= 95.f) ? 1.f : 0.f;
    int cy0 = clampi(iy0, 0, 95), cy1 = clampi(iy0 + 1, 0, 95);
    int cx0 = clampi(ix0, 0, 95), cx1 = clampi(ix0 + 1, 0, 95);
    idx4t[(size_t)k * PIX + p] = make_int4(cy0 * Wc + cx0, cy0 * Wc + cx1,
                                           cy1 * Wc + cx0, cy1 * Wc + cx1);
    wt4t[(size_t)k * PIX + p] = make_float4((1.f - wy) * (1.f - wx) * vy0 * vx0,
                                            (1.f - wy) * wx * vy0 * vx1,
                                            wy * (1.f - wx) * vy1 * vx0,
                                            wy * wx * vy1 * vx1);
}

// Offset conv as f16 MFMA GEMM over NHWC x16, epilogue fuses off_reduce.
// Block: 256 threads (4 waves), tile M=32 (18 real) x N=256 pixels.
__global__ __launch_bounds__(256) void conv_off_mfma_kernel(
    const f16* __restrict__ x16, const f16* __restrict__ woffT,
    const float* __restrict__ b_off,
    int4* __restrict__ idx4t, float4* __restrict__ wt4t)
{
    __shared__ __align__(16) f16 s_a[32 * 32];       // 2KB
    __shared__ __align__(16) f16 s_b[4 * 64 * 32];   // 16KB
    const int bid = blockIdx.x;
    const int swz = (bid & 7) * 18 + (bid >> 3);     // 144 blocks, XCD-chunked
    const int p0 = swz * 256;
    const int imgb = (p0 / HW) * HW;
    const int tid = threadIdx.x, lane = tid & 63, wn = tid >> 6;
    const int pst = p0 + wn * 64 + lane;
    const int hwst = pst - imgb;
    const int hst = hwst / Wc, wst = hwst - hst * Wc;
    const int qa = ((lane >> 4) ^ ((lane >> 1) & 3)) * 8;
    const int qb = (lane >> 1) & 3;

    f32x4 acc[2][4];
#pragma unroll
    for (int mi = 0; mi < 2; ++mi)
#pragma unroll
        for (int ni = 0; ni < 4; ++ni) acc[mi][ni] = (f32x4){0.f, 0.f, 0.f, 0.f};

    for (int k = 0; k < 9; ++k) {
        const int dy = k / 3 - 1, dx = k - (k / 3) * 3 - 1;
        const int yy = hst + dy, xx = wst + dx;
        const bool val = (yy >= 0 && yy < Hc && xx >= 0 && xx < Wc);
        const f16* src = x16 + ((size_t)(imgb + yy * Wc + xx)) * Cc;
        for (int ch = 0; ch < 8; ++ch) {
            const int c0 = ch * 32;
            if (tid < 128) {
                int row = tid >> 2, q = tid & 3;
                const f16* g = woffT + ((size_t)(k * 32 + row)) * Cc + c0
                             + ((q ^ ((tid >> 3) & 3)) * 8);
                __builtin_amdgcn_global_load_lds(
                    (const __attribute__((address_space(1))) void*)g,
                    (__attribute__((address_space(3))) void*)&s_a[tid * 8], 16, 0, 0);
            }
#pragma unroll
            for (int g4 = 0; g4 < 4; ++g4) {
                f16x8 v = {0, 0, 0, 0, 0, 0, 0, 0};
                if (val) v = *(const f16x8*)(src + c0 + g4 * 8);
                *(f16x8*)&s_b[wn * 2048 + lane * 32 + ((g4 ^ qb) * 8)] = v;
            }
            __syncthreads();
            f16x8 af0 = *(const f16x8*)&s_a[((lane & 15)) * 32 + qa];
            f16x8 af1 = *(const f16x8*)&s_a[((16 + (lane & 15))) * 32 + qa];
#pragma unroll
            for (int ni = 0; ni < 4; ++ni) {
                f16x8 bf = *(const f16x8*)&s_b[wn * 2048 + (ni * 16 + (lane & 15)) * 32 + qa];
                acc[0][ni] = __builtin_amdgcn_mfma_f32_16x16x32_f16(af0, bf, acc[0][ni], 0, 0, 0);
                acc[1][ni] = __builtin_amdgcn_mfma_f32_16x16x32_f16(af1, bf, acc[1][ni], 0, 0, 0);
            }
            __syncthreads();
        }
    }
    // epilogue: rows 4g..4g+3 (mi=0) = taps 2g,2g+1 ; rows 16,17 (mi=1,g=0) = tap 8
    const int g = lane >> 4;
#pragma unroll
    for (int ni = 0; ni < 4; ++ni) {
        const int p = p0 + wn * 64 + ni * 16 + (lane & 15);
        const int hwp = p - imgb;
        const int hp = hwp / Wc, wp = hwp - hp * Wc;
        store_tap(2 * g,     hp, wp, acc[0][ni][0] + b_off[4 * g],
                                     acc[0][ni][1] + b_off[4 * g + 1], p, idx4t, wt4t);
        store_tap(2 * g + 1, hp, wp, acc[0][ni][2] + b_off[4 * g + 2],
                                     acc[0][ni][3] + b_off[4 * g + 3], p, idx4t, wt4t);
        if (g == 0)
            store_tap(8, hp, wp, acc[1][ni][0] + b_off[16],
                                 acc[1][ni][1] + b_off[17], p, idx4t, wt4t);
    }
}

// Fused deformable sampling (NHWC f32 gathers) + f16 MFMA GEMM + ReLU.
// Block: 512 threads (8 waves as 4M x 2N), tile 256 outputs x 128 pixels.
__global__ __launch_bounds__(512, 2) void deform_mfma_kernel(
    const float* __restrict__ x32, const f16* __restrict__ wT2,
    const int4* __restrict__ idx4t, const float4* __restrict__ wt4t,
    float* __restrict__ o32, f16* __restrict__ o16, float* __restrict__ oN, int last)
{
    __shared__ __align__(16) f16 s_w[256 * 32];  // 16KB
    __shared__ __align__(16) f16 s_s[128 * 32];  // 8KB
    const int bid = blockIdx.x;
    const int swz = (bid & 7) * 36 + (bid >> 3); // 288 blocks, XCD-chunked
    const int p0 = swz * 128;
    const int imgb = (p0 / HW) * HW;
    const int tid = threadIdx.x, lane = tid & 63, wid = tid >> 6;
    const int wm = wid >> 1, wn = wid & 1;
    const int pp = tid & 127, g4 = tid >> 7;
    const int qa = ((lane >> 4) ^ ((lane >> 1) & 3)) * 8;
    const int qs = ((g4 ^ ((pp >> 1) & 3)) * 8);
    const float* xb = x32 + (size_t)imgb * Cc;

    f32x4 acc[4][4];
#pragma unroll
    for (int mi = 0; mi < 4; ++mi)
#pragma unroll
        for (int ni = 0; ni < 4; ++ni) acc[mi][ni] = (f32x4){0.f, 0.f, 0.f, 0.f};

    for (int k = 0; k < 9; ++k) {
        const int4   id = idx4t[(size_t)k * PIX + p0 + pp];
        const float4 wv = wt4t[(size_t)k * PIX + p0 + pp];
        const float* pA = xb + (size_t)id.x * Cc;
        const float* pB = xb + (size_t)id.y * Cc;
        const float* pC = xb + (size_t)id.z * Cc;
        const float* pD = xb + (size_t)id.w * Cc;
        for (int ch = 0; ch < 8; ++ch) {
            const int c0 = ch * 32;
            // stage weights: 16KB via 2 x global_load_lds(16B) per thread
#pragma unroll
            for (int i = 0; i < 2; ++i) {
                int u = i * 512 + tid;
                int row = u >> 2;
                const f16* gsrc = wT2 + ((size_t)(k * 256 + row)) * Cc + c0
                                + (((u & 3) ^ ((u >> 3) & 3)) * 8);
                __builtin_amdgcn_global_load_lds(
                    (const __attribute__((address_space(1))) void*)gsrc,
                    (__attribute__((address_space(3))) void*)&s_w[u * 8], 16, 0, 0);
            }
            // sample 8 channels for pixel pp: 4 corner float8 reads + blend
            const int coff = c0 + g4 * 8;
            float4 a0 = *(const float4*)(pA + coff), a1 = *(const float4*)(pA + coff + 4);
            float4 b0 = *(const float4*)(pB + coff), b1 = *(const float4*)(pB + coff + 4);
            float4 e0 = *(const float4*)(pC + coff), e1 = *(const float4*)(pC + coff + 4);
            float4 d0 = *(const float4*)(pD + coff), d1 = *(const float4*)(pD + coff + 4);
            f16x8 sv;
#pragma unroll
            for (int j = 0; j < 4; ++j) {
                float lo = wv.x * ((const float*)&a0)[j] + wv.y * ((const float*)&b0)[j]
                         + wv.z * ((const float*)&e0)[j] + wv.w * ((const float*)&d0)[j];
                float hi = wv.x * ((const float*)&a1)[j] + wv.y * ((const float*)&b1)[j]
                         + wv.z * ((const float*)&e1)[j] + wv.w * ((const float*)&d1)[j];
                sv[j] = (f16)lo;
                sv[4 + j] = (f16)hi;
            }
            *(f16x8*)&s_s[pp * 32 + qs] = sv;
            __syncthreads();

            f16x8 af[4], bf[4];
#pragma unroll
            for (int mi = 0; mi < 4; ++mi)
                af[mi] = *(const f16x8*)&s_w[(wm * 64 + mi * 16 + (lane & 15)) * 32 + qa];
#pragma unroll
            for (int ni = 0; ni < 4; ++ni)
                bf[ni] = *(const f16x8*)&s_s[(wn * 64 + ni * 16 + (lane & 15)) * 32 + qa];
#pragma unroll
            for (int ni = 0; ni < 4; ++ni)
#pragma unroll
                for (int mi = 0; mi < 4; ++mi)
                    acc[mi][ni] = __builtin_amdgcn_mfma_f32_16x16x32_f16(
                        af[mi], bf[ni], acc[mi][ni], 0, 0, 0);
            __syncthreads();
        }
    }

    // epilogue: ReLU; D row = output = (lane>>4)*4+j, col = pixel = lane&15
    if (!last) {
#pragma unroll
        for (int ni = 0; ni < 4; ++ni) {
            const int p = p0 + wn * 64 + ni * 16 + (lane & 15);
#pragma unroll
            for (int mi = 0; mi < 4; ++mi) {
                const int o0 = wm * 64 + mi * 16 + (lane >> 4) * 4;
                f32x4 v = acc[mi][ni];
                float4 r = make_float4(fmaxf(v[0], 0.f), fmaxf(v[1], 0.f),
                                       fmaxf(v[2], 0.f), fmaxf(v[3], 0.f));
                *(float4*)&o32[(size_t)p * Cc + o0] = r;
                f16x4 h = {(f16)r.x, (f16)r.y, (f16)r.z, (f16)r.w};
                *(f16x4*)&o16[(size_t)p * Cc + o0] = h;
            }
        }
    } else {
        const int bimg = imgb / HW;
#pragma unroll
        for (int ni = 0; ni < 4; ++ni) {
            const int p = p0 + wn * 64 + ni * 16 + (lane & 15);
            const int hwl = p - imgb;
#pragma unroll
            for (int mi = 0; mi < 4; ++mi) {
                const int o0 = wm * 64 + mi * 16 + (lane >> 4) * 4;
#pragma unroll
                for (int j = 0; j < 4; ++j)
                    oN[((size_t)(bimg * Cc + o0 + j)) * HW + hwl] =
                        fmaxf(acc[mi][ni][j], 0.f);
            }
        }
    }
}

extern "C" void kernel_launch(void* const* d_in, const int* in_sizes, int n_in,
                              void* d_out, int out_size, void* d_ws, size_t ws_size,
                              hipStream_t stream)
{
    const float* x0 = (const float*)d_in[0];
    float* out = (float*)d_out;

    float* x32a = (float*)d_ws;                        // PIX*Cc f32
    float* x32b = x32a + (size_t)PIX * Cc;             // PIX*Cc f32
    f16*   x16  = (f16*)(x32b + (size_t)PIX * Cc);     // PIX*Cc f16
    f16*   wT2  = x16 + (size_t)PIX * Cc;              // CK*Cc f16
    f16*   woffT = wT2 + (size_t)CK * Cc;              // 9*32*256 f16
    int4*  idx4t = (int4*)(woffT + (size_t)9 * 32 * Cc);
    float4* wt4t = (float4*)(idx4t + (size_t)KK * PIX);

    nhwc_prep_kernel<<<dim3(HW / 64, Cc / 64, Bc), 256, 0, stream>>>(x0, x32a, x16);

    const float* xin32 = x32a;
    for (int L = 0; L < 3; ++L) {
        const float* w_off = (const float*)d_in[1 + 3 * L];
        const float* b_off = (const float*)d_in[2 + 3 * L];
        const float* w     = (const float*)d_in[3 + 3 * L];
        const int last = (L == 2);
        float* xo32 = (L == 0) ? x32b : x32a;

        transpose_w_kernel<<<(CK * Cc) / 256, 256, 0, stream>>>(w, wT2);
        woff_prep_kernel<<<(9 * 32 * Cc) / 256, 256, 0, stream>>>(w_off, woffT);
        conv_off_mfma_kernel<<<PIX / 256, 256, 0, stream>>>(x16, woffT, b_off, idx4t, wt4t);
        deform_mfma_kernel<<<PIX / 128, 512, 0, stream>>>(
            xin32, wT2, idx4t, wt4t, xo32, x16, out, last);

        xin32 = xo32;
    }
}

// Round 4
// 741.545 us; speedup vs baseline: 5.0268x; 1.7322x over previous
//
#include <hip/hip_runtime.h>

#define Hc 96
#define Wc 96
#define Cc 256
#define Bc 4
#define KK 9
#define HW 9216          // Hc*Wc
#define PIX 36864        // Bc*HW
#define CK 2304          // Cc*KK

typedef _Float16 f16;
typedef __attribute__((ext_vector_type(4))) _Float16 f16x4;
typedef __attribute__((ext_vector_type(8))) _Float16 f16x8;
typedef __attribute__((ext_vector_type(4))) float f32x4;

__device__ __forceinline__ int clampi(int v, int lo, int hi) {
    return v < lo ? lo : (v > hi ? hi : v);
}

#define SB() __builtin_amdgcn_sched_barrier(0)

// ---------- prep: NCHW fp32 -> NHWC f16 (layer 0 input) ----------
__global__ __launch_bounds__(256) void nhwc_prep_kernel(
    const float* __restrict__ x0, f16* __restrict__ x16)
{
    __shared__ float st[64][65];
    const int hw0 = blockIdx.x * 64;
    const int c0  = blockIdx.y * 64;
    const int b   = blockIdx.z;
    const int tid = threadIdx.x;
    const int a = tid & 63, r = tid >> 6;
#pragma unroll
    for (int it = 0; it < 16; ++it) {
        int cl = it * 4 + r;
        st[cl][a] = x0[((size_t)(b * Cc + c0 + cl)) * HW + hw0 + a];
    }
    __syncthreads();
#pragma unroll
    for (int it = 0; it < 16; ++it) {
        int hwl = it * 4 + r;
        x16[((size_t)(b * HW + hw0 + hwl)) * Cc + c0 + a] = (f16)st[a][hwl];
    }
}

// wT2[(k*256 + o)*256 + c] = (f16) w[(o*256 + c)*9 + k]
__global__ __launch_bounds__(256) void transpose_w_kernel(
    const float* __restrict__ w, f16* __restrict__ wT2)
{
    int u = blockIdx.x * 256 + threadIdx.x;   // < 589824
    int c = u & 255, o = (u >> 8) & 255, k = u >> 16;
    wT2[u] = (f16)w[(o * Cc + c) * KK + k];
}

// woffT[(k*32 + j)*256 + c] = (f16) w_off[(j*256 + c)*9 + k], rows 18..31 = 0
__global__ __launch_bounds__(256) void woff_prep_kernel(
    const float* __restrict__ w_off, f16* __restrict__ woffT)
{
    int u = blockIdx.x * 256 + threadIdx.x;   // < 73728
    int c = u & 255, j = (u >> 8) & 31, k = u >> 13;
    float v = (j < 18) ? w_off[((size_t)j * Cc + c) * KK + k] : 0.f;
    woffT[u] = (f16)v;
}

// bilinear decomposition for one tap -> idx4/wt4 (tap-major layout)
__device__ __forceinline__ void store_tap(int k, int h, int w, float offy, float offx,
    int p, int4* __restrict__ idx4t, float4* __restrict__ wt4t)
{
    float py = (float)(h - 1 + k / 3) + offy;
    float px = (float)(w - 1 + k % 3) + offx;
    float y0f = floorf(py), x0f = floorf(px);
    float wy = py - y0f, wx = px - x0f;
    int iy0 = (int)y0f, ix0 = (int)x0f;
    float vy0 = (y0f >= 0.f && y0f <= 95.f) ? 1.f : 0.f;
    float vy1 = (y0f + 1.f >= 0.f && y0f + 1.f <= 95.f) ? 1.f : 0.f;
    float vx0 = (x0f >= 0.f && x0f <= 95.f) ? 1.f : 0.f;
    float vx1 = (x0f + 1.f >= 0.f && x0f + 1.f <= 95.f) ? 1.f : 0.f;
    int cy0 = clampi(iy0, 0, 95), cy1 = clampi(iy0 + 1, 0, 95);
    int cx0 = clampi(ix0, 0, 95), cx1 = clampi(ix0 + 1, 0, 95);
    idx4t[(size_t)k * PIX + p] = make_int4(cy0 * Wc + cx0, cy0 * Wc + cx1,
                                           cy1 * Wc + cx0, cy1 * Wc + cx1);
    wt4t[(size_t)k * PIX + p] = make_float4((1.f - wy) * (1.f - wx) * vy0 * vx0,
                                            (1.f - wy) * wx * vy0 * vx1,
                                            wy * (1.f - wx) * vy1 * vx0,
                                            wy * wx * vy1 * vx1);
}

// Offset conv as f16 MFMA GEMM over NHWC x16, epilogue fuses off_reduce.
__global__ __launch_bounds__(256) void conv_off_mfma_kernel(
    const f16* __restrict__ x16, const f16* __restrict__ woffT,
    const float* __restrict__ b_off,
    int4* __restrict__ idx4t, float4* __restrict__ wt4t)
{
    __shared__ __align__(16) f16 s_a[32 * 32];       // 2KB
    __shared__ __align__(16) f16 s_b[4 * 64 * 32];   // 16KB
    const int bid = blockIdx.x;
    const int swz = (bid & 7) * 18 + (bid >> 3);     // 144 blocks, XCD-chunked
    const int p0 = swz * 256;
    const int imgb = (p0 / HW) * HW;
    const int tid = threadIdx.x, lane = tid & 63, wn = tid >> 6;
    const int pst = p0 + wn * 64 + lane;
    const int hwst = pst - imgb;
    const int hst = hwst / Wc, wst = hwst - hst * Wc;
    const int qa = ((lane >> 4) ^ ((lane >> 1) & 3)) * 8;
    const int qb = (lane >> 1) & 3;

    f32x4 acc[2][4];
#pragma unroll
    for (int mi = 0; mi < 2; ++mi)
#pragma unroll
        for (int ni = 0; ni < 4; ++ni) acc[mi][ni] = (f32x4){0.f, 0.f, 0.f, 0.f};

    for (int k = 0; k < 9; ++k) {
        const int dy = k / 3 - 1, dx = k - (k / 3) * 3 - 1;
        const int yy = hst + dy, xx = wst + dx;
        const bool val = (yy >= 0 && yy < Hc && xx >= 0 && xx < Wc);
        const f16* src = x16 + ((size_t)(imgb + yy * Wc + xx)) * Cc;
        for (int ch = 0; ch < 8; ++ch) {
            const int c0 = ch * 32;
            if (tid < 128) {
                int row = tid >> 2, q = tid & 3;
                const f16* g = woffT + ((size_t)(k * 32 + row)) * Cc + c0
                             + ((q ^ ((tid >> 3) & 3)) * 8);
                __builtin_amdgcn_global_load_lds(
                    (const __attribute__((address_space(1))) void*)g,
                    (__attribute__((address_space(3))) void*)&s_a[tid * 8], 16, 0, 0);
            }
#pragma unroll
            for (int g4 = 0; g4 < 4; ++g4) {
                f16x8 v = {0, 0, 0, 0, 0, 0, 0, 0};
                if (val) v = *(const f16x8*)(src + c0 + g4 * 8);
                *(f16x8*)&s_b[wn * 2048 + lane * 32 + ((g4 ^ qb) * 8)] = v;
            }
            __syncthreads();
            f16x8 af0 = *(const f16x8*)&s_a[((lane & 15)) * 32 + qa];
            f16x8 af1 = *(const f16x8*)&s_a[((16 + (lane & 15))) * 32 + qa];
#pragma unroll
            for (int ni = 0; ni < 4; ++ni) {
                f16x8 bf = *(const f16x8*)&s_b[wn * 2048 + (ni * 16 + (lane & 15)) * 32 + qa];
                acc[0][ni] = __builtin_amdgcn_mfma_f32_16x16x32_f16(af0, bf, acc[0][ni], 0, 0, 0);
                acc[1][ni] = __builtin_amdgcn_mfma_f32_16x16x32_f16(af1, bf, acc[1][ni], 0, 0, 0);
            }
            __syncthreads();
        }
    }
    const int g = lane >> 4;
#pragma unroll
    for (int ni = 0; ni < 4; ++ni) {
        const int p = p0 + wn * 64 + ni * 16 + (lane & 15);
        const int hwp = p - imgb;
        const int hp = hwp / Wc, wp = hwp - hp * Wc;
        store_tap(2 * g,     hp, wp, acc[0][ni][0] + b_off[4 * g],
                                     acc[0][ni][1] + b_off[4 * g + 1], p, idx4t, wt4t);
        store_tap(2 * g + 1, hp, wp, acc[0][ni][2] + b_off[4 * g + 2],
                                     acc[0][ni][3] + b_off[4 * g + 3], p, idx4t, wt4t);
        if (g == 0)
            store_tap(8, hp, wp, acc[1][ni][0] + b_off[16],
                                 acc[1][ni][1] + b_off[17], p, idx4t, wt4t);
    }
}

// Fused deformable sampling (f16 NHWC gathers) + f16 MFMA GEMM + ReLU.
// Software-pipelined: corners 2 chunks ahead (reg ping-pong), weights 1 chunk
// ahead (LDS double buffer), one raw barrier/chunk with pre-barrier vmcnt(4).
__global__ __launch_bounds__(512, 2) void deform_mfma_kernel(
    const f16* __restrict__ x16, const f16* __restrict__ wT2,
    const int4* __restrict__ idx4t, const float4* __restrict__ wt4t,
    f16* __restrict__ o16, float* __restrict__ oN, int last)
{
    __shared__ __align__(16) f16 s_w[2][8192];  // 2 x 16KB [o(256)][kk(32)] swz
    __shared__ __align__(16) f16 s_s[2][4096];  // 2 x 8KB  [pix(128)][kk(32)] swz

    const int bid = blockIdx.x;
    const int swz = (bid & 7) * 36 + (bid >> 3); // 288 blocks, XCD-chunked
    const int p0 = swz * 128;
    const int imgb = (p0 / HW) * HW;
    const int tid = threadIdx.x, lane = tid & 63, wid = tid >> 6;
    const int wm = wid >> 1, wn = wid & 1;
    const int pp = tid & 127, g4 = tid >> 7;
    const int qa = ((lane >> 4) ^ ((lane >> 1) & 3)) * 8;
    const int qs = (g4 ^ ((pp >> 1) & 3)) * 8;
    const f16* xb = x16 + (size_t)imgb * Cc;
    const int u0 = tid, u1 = 512 + tid;
    const int wc0 = ((u0 & 3) ^ ((u0 >> 3) & 3)) * 8;
    const int wc1 = ((u1 & 3) ^ ((u1 >> 3) & 3)) * 8;
    const int wr0 = u0 >> 2, wr1 = u1 >> 2;

#define ISSUE_W(kt, cw, nb) do {                                               \
    const f16* g0_ = wT2 + ((size_t)((kt) * 256 + wr0)) * Cc + (cw) * 32 + wc0;\
    __builtin_amdgcn_global_load_lds(                                          \
        (const __attribute__((address_space(1))) void*)g0_,                    \
        (__attribute__((address_space(3))) void*)&s_w[nb][u0 * 8], 16, 0, 0);  \
    const f16* g1_ = wT2 + ((size_t)((kt) * 256 + wr1)) * Cc + (cw) * 32 + wc1;\
    __builtin_amdgcn_global_load_lds(                                          \
        (const __attribute__((address_space(1))) void*)g1_,                    \
        (__attribute__((address_space(3))) void*)&s_w[nb][u1 * 8], 16, 0, 0);  \
} while (0)

#define ISSUE_C(dst, idv, co) do {                                             \
    (dst)[0] = *(const f16x8*)(xb + (size_t)(idv).x * Cc + (co));              \
    (dst)[1] = *(const f16x8*)(xb + (size_t)(idv).y * Cc + (co));              \
    (dst)[2] = *(const f16x8*)(xb + (size_t)(idv).z * Cc + (co));              \
    (dst)[3] = *(const f16x8*)(xb + (size_t)(idv).w * Cc + (co));              \
} while (0)

#define BLEND_WRITE(src, wvv, nb) do {                                         \
    f16x8 sv_;                                                                 \
    _Pragma("unroll")                                                          \
    for (int j_ = 0; j_ < 8; ++j_) {                                           \
        float s_ = (wvv).x * (float)(src)[0][j_] + (wvv).y * (float)(src)[1][j_]\
                 + (wvv).z * (float)(src)[2][j_] + (wvv).w * (float)(src)[3][j_];\
        sv_[j_] = (f16)s_;                                                     \
    }                                                                          \
    *(f16x8*)&s_s[nb][pp * 32 + qs] = sv_;                                     \
} while (0)

    f32x4 acc[4][4];
#pragma unroll
    for (int mi = 0; mi < 4; ++mi)
#pragma unroll
        for (int ni = 0; ni < 4; ++ni) acc[mi][ni] = (f32x4){0.f, 0.f, 0.f, 0.f};

    f16x8 c4[2][4];
    int4 id = idx4t[p0 + pp];
    float4 wv = wt4t[p0 + pp];
    int4 idN;
    float4 wvN;

    // prologue: S(0)->s_s[0], W(0,0)->s_w[0], C(0,1) in flight -> c4[0]
    ISSUE_W(0, 0, 0);
    ISSUE_C(c4[1], id, g4 * 8);            // C(tap0, chunk0)
    ISSUE_C(c4[0], id, 32 + g4 * 8);       // C(tap0, chunk1)
    BLEND_WRITE(c4[1], wv, 0);             // compiler-waits c4[1]
    asm volatile("s_waitcnt lgkmcnt(0)" ::: "memory"); SB();
    asm volatile("s_waitcnt vmcnt(4)" ::: "memory");  SB();  // W(0,0) done
    __builtin_amdgcn_s_barrier(); SB();

    for (int k = 0; k < 9; ++k) {
        const int kn = (k < 8) ? k + 1 : 8;
#pragma unroll
        for (int ch = 0; ch < 8; ++ch) {
            const int bb = ch & 1, nb = bb ^ 1;
            // fragments from current buffers
            f16x8 af[4], bf[4];
#pragma unroll
            for (int mi = 0; mi < 4; ++mi)
                af[mi] = *(const f16x8*)&s_w[bb][(wm * 64 + mi * 16 + (lane & 15)) * 32 + qa];
#pragma unroll
            for (int ni = 0; ni < 4; ++ni)
                bf[ni] = *(const f16x8*)&s_s[bb][(wn * 64 + ni * 16 + (lane & 15)) * 32 + qa];
            if (ch == 0) {
                idN = idx4t[(size_t)kn * PIX + p0 + pp];
                wvN = wt4t[(size_t)kn * PIX + p0 + pp];
            }
            // prefetch: weights for t+1 (first), corners for t+2 (after)
            ISSUE_W((ch == 7) ? kn : k, (ch + 1) & 7, nb);
            {
                const int4 idu = (ch >= 6) ? idN : id;
                ISSUE_C(c4[nb], idu, ((ch + 2) & 7) * 32 + g4 * 8);
            }
            // blend C(t+1) (issued last chunk; compiler emits counted vmcnt)
            {
                const float4 wvu = (ch == 7) ? wvN : wv;
                BLEND_WRITE(c4[bb], wvu, nb);
            }
            asm volatile("s_waitcnt lgkmcnt(0)" ::: "memory"); SB();
#pragma unroll
            for (int ni = 0; ni < 4; ++ni)
#pragma unroll
                for (int mi = 0; mi < 4; ++mi)
                    acc[mi][ni] = __builtin_amdgcn_mfma_f32_16x16x32_f16(
                        af[mi], bf[ni], acc[mi][ni], 0, 0, 0);
            // retire this chunk's gload_lds before barrier (leave 4 corners in flight)
            asm volatile("s_waitcnt vmcnt(4)" ::: "memory"); SB();
            __builtin_amdgcn_s_barrier(); SB();
        }
        id = idN;
        wv = wvN;
    }

    // epilogue: ReLU; D row = output = (lane>>4)*4+j, col = pixel = lane&15
    if (!last) {
#pragma unroll
        for (int ni = 0; ni < 4; ++ni) {
            const int p = p0 + wn * 64 + ni * 16 + (lane & 15);
#pragma unroll
            for (int mi = 0; mi < 4; ++mi) {
                const int o0 = wm * 64 + mi * 16 + (lane >> 4) * 4;
                f32x4 v = acc[mi][ni];
                f16x4 h = {(f16)fmaxf(v[0], 0.f), (f16)fmaxf(v[1], 0.f),
                           (f16)fmaxf(v[2], 0.f), (f16)fmaxf(v[3], 0.f)};
                *(f16x4*)&o16[(size_t)p * Cc + o0] = h;
            }
        }
    } else {
        const int bimg = imgb / HW;
#pragma unroll
        for (int ni = 0; ni < 4; ++ni) {
            const int p = p0 + wn * 64 + ni * 16 + (lane & 15);
            const int hwl = p - imgb;
#pragma unroll
            for (int mi = 0; mi < 4; ++mi) {
                const int o0 = wm * 64 + mi * 16 + (lane >> 4) * 4;
#pragma unroll
                for (int j = 0; j < 4; ++j)
                    oN[((size_t)(bimg * Cc + o0 + j)) * HW + hwl] =
                        fmaxf(acc[mi][ni][j], 0.f);
            }
        }
    }
#undef ISSUE_W
#undef ISSUE_C
#undef BLEND_WRITE
}

extern "C" void kernel_launch(void* const* d_in, const int* in_sizes, int n_in,
                              void* d_out, int out_size, void* d_ws, size_t ws_size,
                              hipStream_t stream)
{
    const float* x0 = (const float*)d_in[0];
    float* out = (float*)d_out;

    f16*   x16a = (f16*)d_ws;                          // PIX*Cc f16
    f16*   x16b = x16a + (size_t)PIX * Cc;             // PIX*Cc f16
    f16*   wT2  = x16b + (size_t)PIX * Cc;             // CK*Cc f16
    f16*   woffT = wT2 + (size_t)CK * Cc;              // 9*32*256 f16
    int4*  idx4t = (int4*)(woffT + (size_t)9 * 32 * Cc);
    float4* wt4t = (float4*)(idx4t + (size_t)KK * PIX);

    nhwc_prep_kernel<<<dim3(HW / 64, Cc / 64, Bc), 256, 0, stream>>>(x0, x16a);

    const f16* xin = x16a;
    for (int L = 0; L < 3; ++L) {
        const float* w_off = (const float*)d_in[1 + 3 * L];
        const float* b_off = (const float*)d_in[2 + 3 * L];
        const float* w     = (const float*)d_in[3 + 3 * L];
        const int last = (L == 2);
        f16* xo = (L == 0) ? x16b : x16a;

        transpose_w_kernel<<<(CK * Cc) / 256, 256, 0, stream>>>(w, wT2);
        woff_prep_kernel<<<(9 * 32 * Cc) / 256, 256, 0, stream>>>(w_off, woffT);
        conv_off_mfma_kernel<<<PIX / 256, 256, 0, stream>>>(xin, woffT, b_off, idx4t, wt4t);
        deform_mfma_kernel<<<PIX / 128, 512, 0, stream>>>(
            xin, wT2, idx4t, wt4t, xo, out, last);

        xin = xo;
    }
}

// Round 5
// 569.153 us; speedup vs baseline: 6.5493x; 1.3029x over previous
//
#include <hip/hip_runtime.h>

#define Hc 96
#define Wc 96
#define Cc 256
#define Bc 4
#define KK 9
#define HW 9216          // Hc*Wc
#define PIX 36864        // Bc*HW
#define CK 2304          // Cc*KK

typedef _Float16 f16;
typedef __attribute__((ext_vector_type(4))) _Float16 f16x4;
typedef __attribute__((ext_vector_type(8))) _Float16 f16x8;
typedef __attribute__((ext_vector_type(4))) float f32x4;

__device__ __forceinline__ int clampi(int v, int lo, int hi) {
    return v < lo ? lo : (v > hi ? hi : v);
}

#define SB() __builtin_amdgcn_sched_barrier(0)

// ---------- prep: NCHW fp32 -> NHWC f16 (layer 0 input) ----------
__global__ __launch_bounds__(256) void nhwc_prep_kernel(
    const float* __restrict__ x0, f16* __restrict__ x16)
{
    __shared__ float st[64][65];
    const int hw0 = blockIdx.x * 64;
    const int c0  = blockIdx.y * 64;
    const int b   = blockIdx.z;
    const int tid = threadIdx.x;
    const int a = tid & 63, r = tid >> 6;
#pragma unroll
    for (int it = 0; it < 16; ++it) {
        int cl = it * 4 + r;
        st[cl][a] = x0[((size_t)(b * Cc + c0 + cl)) * HW + hw0 + a];
    }
    __syncthreads();
#pragma unroll
    for (int it = 0; it < 16; ++it) {
        int hwl = it * 4 + r;
        x16[((size_t)(b * HW + hw0 + hwl)) * Cc + c0 + a] = (f16)st[a][hwl];
    }
}

// wT2[(k*256 + o)*256 + c] = (f16) w[(o*256 + c)*9 + k]
__global__ __launch_bounds__(256) void transpose_w_kernel(
    const float* __restrict__ w, f16* __restrict__ wT2)
{
    int u = blockIdx.x * 256 + threadIdx.x;   // < 589824
    int c = u & 255, o = (u >> 8) & 255, k = u >> 16;
    wT2[u] = (f16)w[(o * Cc + c) * KK + k];
}

// woffT[(k*32 + j)*256 + c] = (f16) w_off[(j*256 + c)*9 + k], rows 18..31 = 0
__global__ __launch_bounds__(256) void woff_prep_kernel(
    const float* __restrict__ w_off, f16* __restrict__ woffT)
{
    int u = blockIdx.x * 256 + threadIdx.x;   // < 73728
    int c = u & 255, j = (u >> 8) & 31, k = u >> 13;
    float v = (j < 18) ? w_off[((size_t)j * Cc + c) * KK + k] : 0.f;
    woffT[u] = (f16)v;
}

// bilinear decomposition for one tap -> idx4/wt4 (tap-major layout)
__device__ __forceinline__ void store_tap(int k, int h, int w, float offy, float offx,
    int p, int4* __restrict__ idx4t, float4* __restrict__ wt4t)
{
    float py = (float)(h - 1 + k / 3) + offy;
    float px = (float)(w - 1 + k % 3) + offx;
    float y0f = floorf(py), x0f = floorf(px);
    float wy = py - y0f, wx = px - x0f;
    int iy0 = (int)y0f, ix0 = (int)x0f;
    float vy0 = (y0f >= 0.f && y0f <= 95.f) ? 1.f : 0.f;
    float vy1 = (y0f + 1.f >= 0.f && y0f + 1.f <= 95.f) ? 1.f : 0.f;
    float vx0 = (x0f >= 0.f && x0f <= 95.f) ? 1.f : 0.f;
    float vx1 = (x0f + 1.f >= 0.f && x0f + 1.f <= 95.f) ? 1.f : 0.f;
    int cy0 = clampi(iy0, 0, 95), cy1 = clampi(iy0 + 1, 0, 95);
    int cx0 = clampi(ix0, 0, 95), cx1 = clampi(ix0 + 1, 0, 95);
    idx4t[(size_t)k * PIX + p] = make_int4(cy0 * Wc + cx0, cy0 * Wc + cx1,
                                           cy1 * Wc + cx0, cy1 * Wc + cx1);
    wt4t[(size_t)k * PIX + p] = make_float4((1.f - wy) * (1.f - wx) * vy0 * vx0,
                                            (1.f - wy) * wx * vy0 * vx1,
                                            wy * (1.f - wx) * vy1 * vx0,
                                            wy * wx * vy1 * vx1);
}

// Offset conv as f16 MFMA GEMM, reg-staged double-buffered pipeline.
// Block: 256 threads (4 waves = 2M x 2N), tile 32 out x 64 pixels. 576 blocks.
__global__ __launch_bounds__(256) void conv_off_mfma_kernel(
    const f16* __restrict__ x16, const f16* __restrict__ woffT,
    const float* __restrict__ b_off,
    int4* __restrict__ idx4t, float4* __restrict__ wt4t)
{
    __shared__ __align__(16) f16 s_a[2][32 * 32];   // 2 x 2KB
    __shared__ __align__(16) f16 s_b[2][64 * 32];   // 2 x 4KB
    const int bid = blockIdx.x;
    const int swz = (bid & 7) * 72 + (bid >> 3);    // 576 blocks, XCD-chunked
    const int p0 = swz * 64;
    const int imgb = (p0 / HW) * HW;
    const int tid = threadIdx.x, lane = tid & 63, wid = tid >> 6;
    const int wm = wid >> 1, wn = wid & 1;
    const int qa = ((lane >> 4) ^ ((lane >> 1) & 3)) * 8;
    // A-stage mapping: row/col-quad
    const int arow = tid >> 3, acb = tid & 7;
    const int adst = arow * 32 + (((acb >> 1) ^ ((arow >> 1) & 3)) * 8) + (acb & 1) * 4;
    // B-stage mapping: pixel pp, 8-ch group bg
    const int pp = tid & 63, bg = tid >> 6;
    const int bdst = pp * 32 + ((bg ^ ((pp >> 1) & 3)) * 8);
    const int hwp = p0 + pp - imgb;
    const int hp = hwp / Wc, wp = hwp - hp * Wc;

#define CLOAD(q, aD, bD) do {                                                  \
    int p2_ = (q) > 71 ? 71 : (q);                                             \
    int k2_ = p2_ >> 3, c2_ = p2_ & 7;                                         \
    int ky_ = k2_ / 3, kx_ = k2_ - ky_ * 3;                                    \
    int yy_ = hp + ky_ - 1, xx_ = wp + kx_ - 1;                                \
    bool v_ = (yy_ >= 0 && yy_ < Hc && xx_ >= 0 && xx_ < Wc);                  \
    aD = *(const f16x4*)(woffT + ((size_t)(k2_ * 32 + arow)) * Cc + c2_ * 32 + acb * 4); \
    f16x8 t_ = {0, 0, 0, 0, 0, 0, 0, 0};                                       \
    if (v_) t_ = *(const f16x8*)(x16 + ((size_t)(imgb + yy_ * Wc + xx_)) * Cc + c2_ * 32 + bg * 8); \
    bD = t_;                                                                   \
} while (0)

    f32x4 acc[2];
    acc[0] = (f32x4){0.f, 0.f, 0.f, 0.f};
    acc[1] = (f32x4){0.f, 0.f, 0.f, 0.f};

    f16x4 aR0, aR1;
    f16x8 bR0, bR1;
    // prologue: phase 0 -> slot0 -> s[0]; phase 1 -> slot1 (held in regs)
    CLOAD(0, aR0, bR0);
    CLOAD(1, aR1, bR1);
    *(f16x4*)&s_a[0][adst] = aR0;
    *(f16x8*)&s_b[0][bdst] = bR0;
    asm volatile("s_waitcnt lgkmcnt(0)" ::: "memory"); SB();
    __builtin_amdgcn_s_barrier(); SB();

#define CBODY(p, aCur, bCur, aNxt, bNxt, bc, bn) do {                          \
    f16x8 af = *(const f16x8*)&s_a[bc][(wm * 16 + (lane & 15)) * 32 + qa];     \
    f16x8 bf0 = *(const f16x8*)&s_b[bc][(wn * 32 + (lane & 15)) * 32 + qa];    \
    f16x8 bf1 = *(const f16x8*)&s_b[bc][(wn * 32 + 16 + (lane & 15)) * 32 + qa];\
    CLOAD((p) + 2, aCur, bCur);                                                \
    acc[0] = __builtin_amdgcn_mfma_f32_16x16x32_f16(af, bf0, acc[0], 0, 0, 0); \
    acc[1] = __builtin_amdgcn_mfma_f32_16x16x32_f16(af, bf1, acc[1], 0, 0, 0); \
    *(f16x4*)&s_a[bn][adst] = aNxt;                                            \
    *(f16x8*)&s_b[bn][bdst] = bNxt;                                            \
    asm volatile("s_waitcnt lgkmcnt(0)" ::: "memory"); SB();                   \
    __builtin_amdgcn_s_barrier(); SB();                                        \
} while (0)

    for (int p = 0; p < 72; p += 2) {
        CBODY(p,     aR0, bR0, aR1, bR1, 0, 1);
        CBODY(p + 1, aR1, bR1, aR0, bR0, 1, 0);
    }

    // epilogue: wm=0 -> taps 0..7 (rows 4g..4g+3), wm=1 -> tap 8 (rows 16,17)
    const int g = lane >> 4;
#pragma unroll
    for (int ni = 0; ni < 2; ++ni) {
        const int p = p0 + wn * 32 + ni * 16 + (lane & 15);
        const int hwq = p - imgb;
        const int hq = hwq / Wc, wq = hwq - hq * Wc;
        if (wm == 0) {
            store_tap(2 * g,     hq, wq, acc[ni][0] + b_off[4 * g],
                                         acc[ni][1] + b_off[4 * g + 1], p, idx4t, wt4t);
            store_tap(2 * g + 1, hq, wq, acc[ni][2] + b_off[4 * g + 2],
                                         acc[ni][3] + b_off[4 * g + 3], p, idx4t, wt4t);
        } else if (g == 0) {
            store_tap(8, hq, wq, acc[ni][0] + b_off[16],
                                 acc[ni][1] + b_off[17], p, idx4t, wt4t);
        }
    }
#undef CLOAD
#undef CBODY
}

// Fused deformable sampling (f16 NHWC gathers) + f16 MFMA GEMM + ReLU.
// Block: 256 threads (4 waves), tile 256 out x 64 pix; wave = 64x64. 576 blocks.
// Pipeline: corners 2 chunks ahead (reg ping-pong), weights 1 chunk ahead
// (LDS double buffer), one raw barrier/chunk with pre-barrier vmcnt(4).
__global__ __launch_bounds__(256) void deform_mfma_kernel(
    const f16* __restrict__ x16, const f16* __restrict__ wT2,
    const int4* __restrict__ idx4t, const float4* __restrict__ wt4t,
    f16* __restrict__ o16, float* __restrict__ oN, int last)
{
    __shared__ __align__(16) f16 s_w[2][8192];  // 2 x 16KB [o(256)][kk(32)] swz
    __shared__ __align__(16) f16 s_s[2][2048];  // 2 x 4KB  [pix(64)][kk(32)] swz

    const int bid = blockIdx.x;
    const int swz = (bid & 7) * 72 + (bid >> 3); // 576 blocks, XCD-chunked
    const int p0 = swz * 64;
    const int imgb = (p0 / HW) * HW;
    const int tid = threadIdx.x, lane = tid & 63, wid = tid >> 6;
    const int pp = tid & 63, g4 = tid >> 6;
    const int qa = ((lane >> 4) ^ ((lane >> 1) & 3)) * 8;
    const int qs = (g4 ^ ((pp >> 1) & 3)) * 8;
    const f16* xb = x16 + (size_t)imgb * Cc;

#define ISSUE_W(kt, cw, nb) do {                                               \
    _Pragma("unroll")                                                          \
    for (int i_ = 0; i_ < 4; ++i_) {                                           \
        int u_ = i_ * 256 + tid;                                               \
        int wr_ = u_ >> 2;                                                     \
        int wc_ = ((u_ & 3) ^ ((u_ >> 3) & 3)) * 8;                            \
        const f16* g_ = wT2 + ((size_t)((kt) * 256 + wr_)) * Cc + (cw) * 32 + wc_; \
        __builtin_amdgcn_global_load_lds(                                      \
            (const __attribute__((address_space(1))) void*)g_,                 \
            (__attribute__((address_space(3))) void*)&s_w[nb][u_ * 8], 16, 0, 0); \
    }                                                                          \
} while (0)

#define ISSUE_C(dst, idv, co) do {                                             \
    (dst)[0] = *(const f16x8*)(xb + (size_t)(idv).x * Cc + (co));              \
    (dst)[1] = *(const f16x8*)(xb + (size_t)(idv).y * Cc + (co));              \
    (dst)[2] = *(const f16x8*)(xb + (size_t)(idv).z * Cc + (co));              \
    (dst)[3] = *(const f16x8*)(xb + (size_t)(idv).w * Cc + (co));              \
} while (0)

#define BLEND_WRITE(src, wvv, nb) do {                                         \
    f16x8 sv_;                                                                 \
    _Pragma("unroll")                                                          \
    for (int j_ = 0; j_ < 8; ++j_) {                                           \
        float s_ = (wvv).x * (float)(src)[0][j_] + (wvv).y * (float)(src)[1][j_]\
                 + (wvv).z * (float)(src)[2][j_] + (wvv).w * (float)(src)[3][j_];\
        sv_[j_] = (f16)s_;                                                     \
    }                                                                          \
    *(f16x8*)&s_s[nb][pp * 32 + qs] = sv_;                                     \
} while (0)

    f32x4 acc[4][4];
#pragma unroll
    for (int mi = 0; mi < 4; ++mi)
#pragma unroll
        for (int ni = 0; ni < 4; ++ni) acc[mi][ni] = (f32x4){0.f, 0.f, 0.f, 0.f};

    f16x8 c4[2][4];
    int4 id = idx4t[p0 + pp];
    float4 wv = wt4t[p0 + pp];
    int4 idN;
    float4 wvN;

    // prologue: W(0,0)->s_w[0]; C(0,0)->blend->s_s[0]; C(0,1) left in flight
    ISSUE_W(0, 0, 0);
    ISSUE_C(c4[1], id, g4 * 8);            // C(tap0, chunk0)
    ISSUE_C(c4[0], id, 32 + g4 * 8);       // C(tap0, chunk1)
    BLEND_WRITE(c4[1], wv, 0);             // compiler-waits c4[1] (vmcnt 4)
    asm volatile("s_waitcnt lgkmcnt(0)" ::: "memory"); SB();
    asm volatile("s_waitcnt vmcnt(4)" ::: "memory");  SB();
    __builtin_amdgcn_s_barrier(); SB();

    for (int k = 0; k < 9; ++k) {
        const int kn = (k < 8) ? k + 1 : 8;
#pragma unroll
        for (int ch = 0; ch < 8; ++ch) {
            const int bb = ch & 1, nb = bb ^ 1;
            f16x8 af[4], bf[4];
#pragma unroll
            for (int mi = 0; mi < 4; ++mi)
                af[mi] = *(const f16x8*)&s_w[bb][(wid * 64 + mi * 16 + (lane & 15)) * 32 + qa];
#pragma unroll
            for (int ni = 0; ni < 4; ++ni)
                bf[ni] = *(const f16x8*)&s_s[bb][(ni * 16 + (lane & 15)) * 32 + qa];
            if (ch == 0) {
                idN = idx4t[(size_t)kn * PIX + p0 + pp];
                wvN = wt4t[(size_t)kn * PIX + p0 + pp];
            }
            // prefetch: weights for t+1 (first), corners for t+2 (after)
            ISSUE_W((ch == 7) ? kn : k, (ch + 1) & 7, nb);
            {
                const int4 idu = (ch >= 6) ? idN : id;
                ISSUE_C(c4[nb], idu, ((ch + 2) & 7) * 32 + g4 * 8);
            }
            // blend C(t+1) (issued last chunk; compiler emits counted vmcnt)
            {
                const float4 wvu = (ch == 7) ? wvN : wv;
                BLEND_WRITE(c4[bb], wvu, nb);
            }
            asm volatile("s_waitcnt lgkmcnt(0)" ::: "memory"); SB();
#pragma unroll
            for (int ni = 0; ni < 4; ++ni)
#pragma unroll
                for (int mi = 0; mi < 4; ++mi)
                    acc[mi][ni] = __builtin_amdgcn_mfma_f32_16x16x32_f16(
                        af[mi], bf[ni], acc[mi][ni], 0, 0, 0);
            // retire this chunk's gload_lds before barrier (4 corners stay in flight)
            asm volatile("s_waitcnt vmcnt(4)" ::: "memory"); SB();
            __builtin_amdgcn_s_barrier(); SB();
        }
        id = idN;
        wv = wvN;
    }

    // epilogue: ReLU; D row = output = (lane>>4)*4+j, col = pixel = lane&15
    if (!last) {
#pragma unroll
        for (int ni = 0; ni < 4; ++ni) {
            const int p = p0 + ni * 16 + (lane & 15);
#pragma unroll
            for (int mi = 0; mi < 4; ++mi) {
                const int o0 = wid * 64 + mi * 16 + (lane >> 4) * 4;
                f32x4 v = acc[mi][ni];
                f16x4 h = {(f16)fmaxf(v[0], 0.f), (f16)fmaxf(v[1], 0.f),
                           (f16)fmaxf(v[2], 0.f), (f16)fmaxf(v[3], 0.f)};
                *(f16x4*)&o16[(size_t)p * Cc + o0] = h;
            }
        }
    } else {
        const int bimg = imgb / HW;
#pragma unroll
        for (int ni = 0; ni < 4; ++ni) {
            const int p = p0 + ni * 16 + (lane & 15);
            const int hwl = p - imgb;
#pragma unroll
            for (int mi = 0; mi < 4; ++mi) {
                const int o0 = wid * 64 + mi * 16 + (lane >> 4) * 4;
#pragma unroll
                for (int j = 0; j < 4; ++j)
                    oN[((size_t)(bimg * Cc + o0 + j)) * HW + hwl] =
                        fmaxf(acc[mi][ni][j], 0.f);
            }
        }
    }
#undef ISSUE_W
#undef ISSUE_C
#undef BLEND_WRITE
}

extern "C" void kernel_launch(void* const* d_in, const int* in_sizes, int n_in,
                              void* d_out, int out_size, void* d_ws, size_t ws_size,
                              hipStream_t stream)
{
    const float* x0 = (const float*)d_in[0];
    float* out = (float*)d_out;

    f16*   x16a = (f16*)d_ws;                          // PIX*Cc f16
    f16*   x16b = x16a + (size_t)PIX * Cc;             // PIX*Cc f16
    f16*   wT2  = x16b + (size_t)PIX * Cc;             // CK*Cc f16
    f16*   woffT = wT2 + (size_t)CK * Cc;              // 9*32*256 f16
    int4*  idx4t = (int4*)(woffT + (size_t)9 * 32 * Cc);
    float4* wt4t = (float4*)(idx4t + (size_t)KK * PIX);

    nhwc_prep_kernel<<<dim3(HW / 64, Cc / 64, Bc), 256, 0, stream>>>(x0, x16a);

    const f16* xin = x16a;
    for (int L = 0; L < 3; ++L) {
        const float* w_off = (const float*)d_in[1 + 3 * L];
        const float* b_off = (const float*)d_in[2 + 3 * L];
        const float* w     = (const float*)d_in[3 + 3 * L];
        const int last = (L == 2);
        f16* xo = (L == 0) ? x16b : x16a;

        transpose_w_kernel<<<(CK * Cc) / 256, 256, 0, stream>>>(w, wT2);
        woff_prep_kernel<<<(9 * 32 * Cc) / 256, 256, 0, stream>>>(w_off, woffT);
        conv_off_mfma_kernel<<<PIX / 64, 256, 0, stream>>>(xin, woffT, b_off, idx4t, wt4t);
        deform_mfma_kernel<<<PIX / 64, 256, 0, stream>>>(
            xin, wT2, idx4t, wt4t, xo, out, last);

        xin = xo;
    }
}

// Round 6
// 451.935 us; speedup vs baseline: 8.2480x; 1.2594x over previous
//
#include <hip/hip_runtime.h>

#define Hc 96
#define Wc 96
#define Cc 256
#define Bc 4
#define KK 9
#define HW 9216          // Hc*Wc
#define PIX 36864        // Bc*HW
#define CK 2304          // Cc*KK

typedef _Float16 f16;
typedef __attribute__((ext_vector_type(4))) _Float16 f16x4;
typedef __attribute__((ext_vector_type(8))) _Float16 f16x8;
typedef __attribute__((ext_vector_type(4))) float f32x4;

__device__ __forceinline__ int clampi(int v, int lo, int hi) {
    return v < lo ? lo : (v > hi ? hi : v);
}

#define SB() __builtin_amdgcn_sched_barrier(0)

// ---------- prep: NCHW fp32 -> NHWC f16 (layer 0 input) ----------
__global__ __launch_bounds__(256) void nhwc_prep_kernel(
    const float* __restrict__ x0, f16* __restrict__ x16)
{
    __shared__ float st[64][65];
    const int hw0 = blockIdx.x * 64;
    const int c0  = blockIdx.y * 64;
    const int b   = blockIdx.z;
    const int tid = threadIdx.x;
    const int a = tid & 63, r = tid >> 6;
#pragma unroll
    for (int it = 0; it < 16; ++it) {
        int cl = it * 4 + r;
        st[cl][a] = x0[((size_t)(b * Cc + c0 + cl)) * HW + hw0 + a];
    }
    __syncthreads();
#pragma unroll
    for (int it = 0; it < 16; ++it) {
        int hwl = it * 4 + r;
        x16[((size_t)(b * HW + hw0 + hwl)) * Cc + c0 + a] = (f16)st[a][hwl];
    }
}

// wT2[(k*256 + o)*256 + c] = (f16) w[(o*256 + c)*9 + k]
__global__ __launch_bounds__(256) void transpose_w_kernel(
    const float* __restrict__ w, f16* __restrict__ wT2)
{
    int u = blockIdx.x * 256 + threadIdx.x;   // < 589824
    int c = u & 255, o = (u >> 8) & 255, k = u >> 16;
    wT2[u] = (f16)w[(o * Cc + c) * KK + k];
}

// woffT[(k*32 + j)*256 + c] = (f16) w_off[(j*256 + c)*9 + k], rows 18..31 = 0
__global__ __launch_bounds__(256) void woff_prep_kernel(
    const float* __restrict__ w_off, f16* __restrict__ woffT)
{
    int u = blockIdx.x * 256 + threadIdx.x;   // < 73728
    int c = u & 255, j = (u >> 8) & 31, k = u >> 13;
    float v = (j < 18) ? w_off[((size_t)j * Cc + c) * KK + k] : 0.f;
    woffT[u] = (f16)v;
}

// bilinear decomposition for one tap -> idx4/wt4 (tap-major layout)
__device__ __forceinline__ void store_tap(int k, int h, int w, float offy, float offx,
    int p, int4* __restrict__ idx4t, float4* __restrict__ wt4t)
{
    float py = (float)(h - 1 + k / 3) + offy;
    float px = (float)(w - 1 + k % 3) + offx;
    float y0f = floorf(py), x0f = floorf(px);
    float wy = py - y0f, wx = px - x0f;
    int iy0 = (int)y0f, ix0 = (int)x0f;
    float vy0 = (y0f >= 0.f && y0f <= 95.f) ? 1.f : 0.f;
    float vy1 = (y0f + 1.f >= 0.f && y0f + 1.f <= 95.f) ? 1.f : 0.f;
    float vx0 = (x0f >= 0.f && x0f <= 95.f) ? 1.f : 0.f;
    float vx1 = (x0f + 1.f >= 0.f && x0f + 1.f <= 95.f) ? 1.f : 0.f;
    int cy0 = clampi(iy0, 0, 95), cy1 = clampi(iy0 + 1, 0, 95);
    int cx0 = clampi(ix0, 0, 95), cx1 = clampi(ix0 + 1, 0, 95);
    idx4t[(size_t)k * PIX + p] = make_int4(cy0 * Wc + cx0, cy0 * Wc + cx1,
                                           cy1 * Wc + cx0, cy1 * Wc + cx1);
    wt4t[(size_t)k * PIX + p] = make_float4((1.f - wy) * (1.f - wx) * vy0 * vx0,
                                            (1.f - wy) * wx * vy0 * vx1,
                                            wy * (1.f - wx) * vy1 * vx0,
                                            wy * wx * vy1 * vx1);
}

// Offset conv as f16 MFMA GEMM, reg-staged double-buffered pipeline.
// Block: 256 threads (4 waves = 2M x 2N), tile 32 out x 64 pixels. 576 blocks.
__global__ __launch_bounds__(256) void conv_off_mfma_kernel(
    const f16* __restrict__ x16, const f16* __restrict__ woffT,
    const float* __restrict__ b_off,
    int4* __restrict__ idx4t, float4* __restrict__ wt4t)
{
    __shared__ __align__(16) f16 s_a[2][32 * 32];   // 2 x 2KB
    __shared__ __align__(16) f16 s_b[2][64 * 32];   // 2 x 4KB
    const int bid = blockIdx.x;
    const int swz = (bid & 7) * 72 + (bid >> 3);    // 576 blocks, XCD-chunked
    const int p0 = swz * 64;
    const int imgb = (p0 / HW) * HW;
    const int tid = threadIdx.x, lane = tid & 63, wid = tid >> 6;
    const int wm = wid >> 1, wn = wid & 1;
    const int qa = ((lane >> 4) ^ ((lane >> 1) & 3)) * 8;
    // A-stage mapping: row/col-quad
    const int arow = tid >> 3, acb = tid & 7;
    const int adst = arow * 32 + (((acb >> 1) ^ ((arow >> 1) & 3)) * 8) + (acb & 1) * 4;
    // B-stage mapping: 4 lanes per pixel (coalesced 64B), pixel ps, group cg
    const int ps = tid >> 2, cg = tid & 3;
    const int bdst = ps * 32 + ((cg ^ ((ps >> 1) & 3)) * 8);
    const int hwp = p0 + ps - imgb;
    const int hp = hwp / Wc, wp = hwp - hp * Wc;

#define CLOAD(q, aD, bD) do {                                                  \
    int p2_ = (q) > 71 ? 71 : (q);                                             \
    int k2_ = p2_ >> 3, c2_ = p2_ & 7;                                         \
    int ky_ = k2_ / 3, kx_ = k2_ - ky_ * 3;                                    \
    int yy_ = hp + ky_ - 1, xx_ = wp + kx_ - 1;                                \
    bool v_ = (yy_ >= 0 && yy_ < Hc && xx_ >= 0 && xx_ < Wc);                  \
    aD = *(const f16x4*)(woffT + ((size_t)(k2_ * 32 + arow)) * Cc + c2_ * 32 + acb * 4); \
    f16x8 t_ = {0, 0, 0, 0, 0, 0, 0, 0};                                       \
    if (v_) t_ = *(const f16x8*)(x16 + ((size_t)(imgb + yy_ * Wc + xx_)) * Cc + c2_ * 32 + cg * 8); \
    bD = t_;                                                                   \
} while (0)

    f32x4 acc[2];
    acc[0] = (f32x4){0.f, 0.f, 0.f, 0.f};
    acc[1] = (f32x4){0.f, 0.f, 0.f, 0.f};

    f16x4 aR0, aR1;
    f16x8 bR0, bR1;
    // prologue: phase 0 -> slot0 -> s[0]; phase 1 -> slot1 (held in regs)
    CLOAD(0, aR0, bR0);
    CLOAD(1, aR1, bR1);
    *(f16x4*)&s_a[0][adst] = aR0;
    *(f16x8*)&s_b[0][bdst] = bR0;
    asm volatile("s_waitcnt lgkmcnt(0)" ::: "memory"); SB();
    __builtin_amdgcn_s_barrier(); SB();

#define CBODY(p, aCur, bCur, aNxt, bNxt, bc, bn) do {                          \
    f16x8 af = *(const f16x8*)&s_a[bc][(wm * 16 + (lane & 15)) * 32 + qa];     \
    f16x8 bf0 = *(const f16x8*)&s_b[bc][(wn * 32 + (lane & 15)) * 32 + qa];    \
    f16x8 bf1 = *(const f16x8*)&s_b[bc][(wn * 32 + 16 + (lane & 15)) * 32 + qa];\
    CLOAD((p) + 2, aCur, bCur);                                                \
    acc[0] = __builtin_amdgcn_mfma_f32_16x16x32_f16(af, bf0, acc[0], 0, 0, 0); \
    acc[1] = __builtin_amdgcn_mfma_f32_16x16x32_f16(af, bf1, acc[1], 0, 0, 0); \
    *(f16x4*)&s_a[bn][adst] = aNxt;                                            \
    *(f16x8*)&s_b[bn][bdst] = bNxt;                                            \
    asm volatile("s_waitcnt lgkmcnt(0)" ::: "memory"); SB();                   \
    __builtin_amdgcn_s_barrier(); SB();                                        \
} while (0)

    for (int p = 0; p < 72; p += 2) {
        CBODY(p,     aR0, bR0, aR1, bR1, 0, 1);
        CBODY(p + 1, aR1, bR1, aR0, bR0, 1, 0);
    }

    // epilogue: wm=0 -> taps 0..7 (rows 4g..4g+3), wm=1 -> tap 8 (rows 16,17)
    const int g = lane >> 4;
#pragma unroll
    for (int ni = 0; ni < 2; ++ni) {
        const int p = p0 + wn * 32 + ni * 16 + (lane & 15);
        const int hwq = p - imgb;
        const int hq = hwq / Wc, wq = hwq - hq * Wc;
        if (wm == 0) {
            store_tap(2 * g,     hq, wq, acc[ni][0] + b_off[4 * g],
                                         acc[ni][1] + b_off[4 * g + 1], p, idx4t, wt4t);
            store_tap(2 * g + 1, hq, wq, acc[ni][2] + b_off[4 * g + 2],
                                         acc[ni][3] + b_off[4 * g + 3], p, idx4t, wt4t);
        } else if (g == 0) {
            store_tap(8, hq, wq, acc[ni][0] + b_off[16],
                                 acc[ni][1] + b_off[17], p, idx4t, wt4t);
        }
    }
#undef CLOAD
#undef CBODY
}

// Fused deformable sampling (f16 NHWC gathers) + f16 MFMA GEMM + ReLU.
// Block: 256 threads (4 waves), tile 256 out x 64 pix; wave = 64x64. 576 blocks.
// Sampling decomposition: 4 lanes per pixel -> each corner gather instruction
// reads contiguous 64B per pixel (coalesced), 16 segments/wave instead of 64.
// Pipeline: corners 1 chunk ahead (reg ping-pong), weights 1 chunk ahead
// (LDS double buffer), one raw barrier/chunk with pre-barrier vmcnt(4).
__global__ __launch_bounds__(256) void deform_mfma_kernel(
    const f16* __restrict__ x16, const f16* __restrict__ wT2,
    const int4* __restrict__ idx4t, const float4* __restrict__ wt4t,
    f16* __restrict__ o16, float* __restrict__ oN, int last)
{
    __shared__ __align__(16) f16 s_w[2][8192];  // 2 x 16KB [o(256)][kk(32)] swz
    __shared__ __align__(16) f16 s_s[2][2048];  // 2 x 4KB  [pix(64)][kk(32)] swz

    const int bid = blockIdx.x;
    const int swz = (bid & 7) * 72 + (bid >> 3); // 576 blocks, XCD-chunked
    const int p0 = swz * 64;
    const int imgb = (p0 / HW) * HW;
    const int tid = threadIdx.x, lane = tid & 63, wid = tid >> 6;
    const int ps = tid >> 2, cg = tid & 3;       // sampling: pixel ps, 8-ch grp cg
    const int qa = ((lane >> 4) ^ ((lane >> 1) & 3)) * 8;
    const int qs = (cg ^ ((ps >> 1) & 3)) * 8;
    const f16* xb = x16 + (size_t)imgb * Cc;

#define ISSUE_W(kt, cw, nb) do {                                               \
    _Pragma("unroll")                                                          \
    for (int i_ = 0; i_ < 4; ++i_) {                                           \
        int u_ = i_ * 256 + tid;                                               \
        int wr_ = u_ >> 2;                                                     \
        int wc_ = ((u_ & 3) ^ ((u_ >> 3) & 3)) * 8;                            \
        const f16* g_ = wT2 + ((size_t)((kt) * 256 + wr_)) * Cc + (cw) * 32 + wc_; \
        __builtin_amdgcn_global_load_lds(                                      \
            (const __attribute__((address_space(1))) void*)g_,                 \
            (__attribute__((address_space(3))) void*)&s_w[nb][u_ * 8], 16, 0, 0); \
    }                                                                          \
} while (0)

// 4 lanes (cg=0..3) of pixel ps read contiguous 64B per corner
#define ISSUE_C(dst, idv, co) do {                                             \
    (dst)[0] = *(const f16x8*)(xb + (size_t)(idv).x * Cc + (co) + cg * 8);     \
    (dst)[1] = *(const f16x8*)(xb + (size_t)(idv).y * Cc + (co) + cg * 8);     \
    (dst)[2] = *(const f16x8*)(xb + (size_t)(idv).z * Cc + (co) + cg * 8);     \
    (dst)[3] = *(const f16x8*)(xb + (size_t)(idv).w * Cc + (co) + cg * 8);     \
} while (0)

#define BLEND_WRITE(src, wvv, nb) do {                                         \
    f16x8 sv_;                                                                 \
    _Pragma("unroll")                                                          \
    for (int j_ = 0; j_ < 8; ++j_) {                                           \
        float s_ = (wvv).x * (float)(src)[0][j_] + (wvv).y * (float)(src)[1][j_]\
                 + (wvv).z * (float)(src)[2][j_] + (wvv).w * (float)(src)[3][j_];\
        sv_[j_] = (f16)s_;                                                     \
    }                                                                          \
    *(f16x8*)&s_s[nb][ps * 32 + qs] = sv_;                                     \
} while (0)

    f32x4 acc[4][4];
#pragma unroll
    for (int mi = 0; mi < 4; ++mi)
#pragma unroll
        for (int ni = 0; ni < 4; ++ni) acc[mi][ni] = (f32x4){0.f, 0.f, 0.f, 0.f};

    f16x8 c4[2][4];
    int4 id = idx4t[p0 + ps];
    float4 wv = wt4t[p0 + ps];
    int4 idN;
    float4 wvN;

    // prologue: W(0,0)->s_w[0]; C(0,0)->blend->s_s[0]; C(0,1) left in flight
    ISSUE_W(0, 0, 0);
    ISSUE_C(c4[1], id, 0);                 // C(tap0, chunk0)
    ISSUE_C(c4[0], id, 32);                // C(tap0, chunk1)
    BLEND_WRITE(c4[1], wv, 0);             // compiler-waits c4[1] (vmcnt 4)
    asm volatile("s_waitcnt lgkmcnt(0)" ::: "memory"); SB();
    asm volatile("s_waitcnt vmcnt(4)" ::: "memory");  SB();
    __builtin_amdgcn_s_barrier(); SB();

    for (int k = 0; k < 9; ++k) {
        const int kn = (k < 8) ? k + 1 : 8;
#pragma unroll
        for (int ch = 0; ch < 8; ++ch) {
            const int bb = ch & 1, nb = bb ^ 1;
            f16x8 af[4], bf[4];
#pragma unroll
            for (int mi = 0; mi < 4; ++mi)
                af[mi] = *(const f16x8*)&s_w[bb][(wid * 64 + mi * 16 + (lane & 15)) * 32 + qa];
#pragma unroll
            for (int ni = 0; ni < 4; ++ni)
                bf[ni] = *(const f16x8*)&s_s[bb][(ni * 16 + (lane & 15)) * 32 + qa];
            if (ch == 0) {
                idN = idx4t[(size_t)kn * PIX + p0 + ps];
                wvN = wt4t[(size_t)kn * PIX + p0 + ps];
            }
            // prefetch: weights for t+1 (first), corners for t+2 (after)
            ISSUE_W((ch == 7) ? kn : k, (ch + 1) & 7, nb);
            {
                const int4 idu = (ch >= 6) ? idN : id;
                ISSUE_C(c4[nb], idu, ((ch + 2) & 7) * 32);
            }
            // blend C(t+1) (issued last chunk; compiler emits counted vmcnt)
            {
                const float4 wvu = (ch == 7) ? wvN : wv;
                BLEND_WRITE(c4[bb], wvu, nb);
            }
            asm volatile("s_waitcnt lgkmcnt(0)" ::: "memory"); SB();
#pragma unroll
            for (int ni = 0; ni < 4; ++ni)
#pragma unroll
                for (int mi = 0; mi < 4; ++mi)
                    acc[mi][ni] = __builtin_amdgcn_mfma_f32_16x16x32_f16(
                        af[mi], bf[ni], acc[mi][ni], 0, 0, 0);
            // retire this chunk's gload_lds before barrier (4 corners stay in flight)
            asm volatile("s_waitcnt vmcnt(4)" ::: "memory"); SB();
            __builtin_amdgcn_s_barrier(); SB();
        }
        id = idN;
        wv = wvN;
    }

    // epilogue: ReLU; D row = output = (lane>>4)*4+j, col = pixel = lane&15
    if (!last) {
#pragma unroll
        for (int ni = 0; ni < 4; ++ni) {
            const int p = p0 + ni * 16 + (lane & 15);
#pragma unroll
            for (int mi = 0; mi < 4; ++mi) {
                const int o0 = wid * 64 + mi * 16 + (lane >> 4) * 4;
                f32x4 v = acc[mi][ni];
                f16x4 h = {(f16)fmaxf(v[0], 0.f), (f16)fmaxf(v[1], 0.f),
                           (f16)fmaxf(v[2], 0.f), (f16)fmaxf(v[3], 0.f)};
                *(f16x4*)&o16[(size_t)p * Cc + o0] = h;
            }
        }
    } else {
        const int bimg = imgb / HW;
#pragma unroll
        for (int ni = 0; ni < 4; ++ni) {
            const int p = p0 + ni * 16 + (lane & 15);
            const int hwl = p - imgb;
#pragma unroll
            for (int mi = 0; mi < 4; ++mi) {
                const int o0 = wid * 64 + mi * 16 + (lane >> 4) * 4;
#pragma unroll
                for (int j = 0; j < 4; ++j)
                    oN[((size_t)(bimg * Cc + o0 + j)) * HW + hwl] =
                        fmaxf(acc[mi][ni][j], 0.f);
            }
        }
    }
#undef ISSUE_W
#undef ISSUE_C
#undef BLEND_WRITE
}

extern "C" void kernel_launch(void* const* d_in, const int* in_sizes, int n_in,
                              void* d_out, int out_size, void* d_ws, size_t ws_size,
                              hipStream_t stream)
{
    const float* x0 = (const float*)d_in[0];
    float* out = (float*)d_out;

    f16*   x16a = (f16*)d_ws;                          // PIX*Cc f16
    f16*   x16b = x16a + (size_t)PIX * Cc;             // PIX*Cc f16
    f16*   wT2  = x16b + (size_t)PIX * Cc;             // CK*Cc f16
    f16*   woffT = wT2 + (size_t)CK * Cc;              // 9*32*256 f16
    int4*  idx4t = (int4*)(woffT + (size_t)9 * 32 * Cc);
    float4* wt4t = (float4*)(idx4t + (size_t)KK * PIX);

    nhwc_prep_kernel<<<dim3(HW / 64, Cc / 64, Bc), 256, 0, stream>>>(x0, x16a);

    const f16* xin = x16a;
    for (int L = 0; L < 3; ++L) {
        const float* w_off = (const float*)d_in[1 + 3 * L];
        const float* b_off = (const float*)d_in[2 + 3 * L];
        const float* w     = (const float*)d_in[3 + 3 * L];
        const int last = (L == 2);
        f16* xo = (L == 0) ? x16b : x16a;

        transpose_w_kernel<<<(CK * Cc) / 256, 256, 0, stream>>>(w, wT2);
        woff_prep_kernel<<<(9 * 32 * Cc) / 256, 256, 0, stream>>>(w_off, woffT);
        conv_off_mfma_kernel<<<PIX / 64, 256, 0, stream>>>(xin, woffT, b_off, idx4t, wt4t);
        deform_mfma_kernel<<<PIX / 64, 256, 0, stream>>>(
            xin, wT2, idx4t, wt4t, xo, out, last);

        xin = xo;
    }
}

// Round 7
// 428.134 us; speedup vs baseline: 8.7066x; 1.0556x over previous
//
#include <hip/hip_runtime.h>

#define Hc 96
#define Wc 96
#define Cc 256
#define Bc 4
#define KK 9
#define HW 9216          // Hc*Wc
#define PIX 36864        // Bc*HW
#define CK 2304          // Cc*KK

typedef _Float16 f16;
typedef __attribute__((ext_vector_type(4))) _Float16 f16x4;
typedef __attribute__((ext_vector_type(8))) _Float16 f16x8;
typedef __attribute__((ext_vector_type(4))) float f32x4;

__device__ __forceinline__ int clampi(int v, int lo, int hi) {
    return v < lo ? lo : (v > hi ? hi : v);
}

#define SB() __builtin_amdgcn_sched_barrier(0)

// ---------- prep: NCHW fp32 -> NHWC f16 (layer 0 input) ----------
__global__ __launch_bounds__(256) void nhwc_prep_kernel(
    const float* __restrict__ x0, f16* __restrict__ x16)
{
    __shared__ float st[64][65];
    const int hw0 = blockIdx.x * 64;
    const int c0  = blockIdx.y * 64;
    const int b   = blockIdx.z;
    const int tid = threadIdx.x;
    const int a = tid & 63, r = tid >> 6;
#pragma unroll
    for (int it = 0; it < 16; ++it) {
        int cl = it * 4 + r;
        st[cl][a] = x0[((size_t)(b * Cc + c0 + cl)) * HW + hw0 + a];
    }
    __syncthreads();
#pragma unroll
    for (int it = 0; it < 16; ++it) {
        int hwl = it * 4 + r;
        x16[((size_t)(b * HW + hw0 + hwl)) * Cc + c0 + a] = (f16)st[a][hwl];
    }
}

// wT2[(k*256 + o)*256 + c] = (f16) w[(o*256 + c)*9 + k]
__global__ __launch_bounds__(256) void transpose_w_kernel(
    const float* __restrict__ w, f16* __restrict__ wT2)
{
    int u = blockIdx.x * 256 + threadIdx.x;   // < 589824
    int c = u & 255, o = (u >> 8) & 255, k = u >> 16;
    wT2[u] = (f16)w[(o * Cc + c) * KK + k];
}

// woffT[(k*32 + j)*256 + c] = (f16) w_off[(j*256 + c)*9 + k], rows 18..31 = 0
__global__ __launch_bounds__(256) void woff_prep_kernel(
    const float* __restrict__ w_off, f16* __restrict__ woffT)
{
    int u = blockIdx.x * 256 + threadIdx.x;   // < 73728
    int c = u & 255, j = (u >> 8) & 31, k = u >> 13;
    float v = (j < 18) ? w_off[((size_t)j * Cc + c) * KK + k] : 0.f;
    woffT[u] = (f16)v;
}

// bilinear decomposition for one tap -> idx4/wt4 (tap-major layout)
__device__ __forceinline__ void store_tap(int k, int h, int w, float offy, float offx,
    int p, int4* __restrict__ idx4t, float4* __restrict__ wt4t)
{
    float py = (float)(h - 1 + k / 3) + offy;
    float px = (float)(w - 1 + k % 3) + offx;
    float y0f = floorf(py), x0f = floorf(px);
    float wy = py - y0f, wx = px - x0f;
    int iy0 = (int)y0f, ix0 = (int)x0f;
    float vy0 = (y0f >= 0.f && y0f <= 95.f) ? 1.f : 0.f;
    float vy1 = (y0f + 1.f >= 0.f && y0f + 1.f <= 95.f) ? 1.f : 0.f;
    float vx0 = (x0f >= 0.f && x0f <= 95.f) ? 1.f : 0.f;
    float vx1 = (x0f + 1.f >= 0.f && x0f + 1.f <= 95.f) ? 1.f : 0.f;
    int cy0 = clampi(iy0, 0, 95), cy1 = clampi(iy0 + 1, 0, 95);
    int cx0 = clampi(ix0, 0, 95), cx1 = clampi(ix0 + 1, 0, 95);
    idx4t[(size_t)k * PIX + p] = make_int4(cy0 * Wc + cx0, cy0 * Wc + cx1,
                                           cy1 * Wc + cx0, cy1 * Wc + cx1);
    wt4t[(size_t)k * PIX + p] = make_float4((1.f - wy) * (1.f - wx) * vy0 * vx0,
                                            (1.f - wy) * wx * vy0 * vx1,
                                            wy * (1.f - wx) * vy1 * vx0,
                                            wy * wx * vy1 * vx1);
}

// Offset conv as f16 MFMA GEMM, reg-staged double-buffered pipeline.
// Block: 256 threads (4 waves = 2M x 2N), tile 32 out x 64 pixels. 576 blocks.
__global__ __launch_bounds__(256) void conv_off_mfma_kernel(
    const f16* __restrict__ x16, const f16* __restrict__ woffT,
    const float* __restrict__ b_off,
    int4* __restrict__ idx4t, float4* __restrict__ wt4t)
{
    __shared__ __align__(16) f16 s_a[2][32 * 32];   // 2 x 2KB
    __shared__ __align__(16) f16 s_b[2][64 * 32];   // 2 x 4KB
    const int bid = blockIdx.x;
    const int swz = (bid & 7) * 72 + (bid >> 3);    // 576 blocks, XCD-chunked
    const int p0 = swz * 64;
    const int imgb = (p0 / HW) * HW;
    const int tid = threadIdx.x, lane = tid & 63, wid = tid >> 6;
    const int wm = wid >> 1, wn = wid & 1;
    const int qa = ((lane >> 4) ^ ((lane >> 1) & 3)) * 8;
    // A-stage mapping: row/col-quad
    const int arow = tid >> 3, acb = tid & 7;
    const int adst = arow * 32 + (((acb >> 1) ^ ((arow >> 1) & 3)) * 8) + (acb & 1) * 4;
    // B-stage mapping: 4 lanes per pixel (coalesced 64B), pixel ps, group cg
    const int ps = tid >> 2, cg = tid & 3;
    const int bdst = ps * 32 + ((cg ^ ((ps >> 1) & 3)) * 8);
    const int hwp = p0 + ps - imgb;
    const int hp = hwp / Wc, wp = hwp - hp * Wc;

#define CLOAD(q, aD, bD) do {                                                  \
    int p2_ = (q) > 71 ? 71 : (q);                                             \
    int k2_ = p2_ >> 3, c2_ = p2_ & 7;                                         \
    int ky_ = k2_ / 3, kx_ = k2_ - ky_ * 3;                                    \
    int yy_ = hp + ky_ - 1, xx_ = wp + kx_ - 1;                                \
    bool v_ = (yy_ >= 0 && yy_ < Hc && xx_ >= 0 && xx_ < Wc);                  \
    aD = *(const f16x4*)(woffT + ((size_t)(k2_ * 32 + arow)) * Cc + c2_ * 32 + acb * 4); \
    f16x8 t_ = {0, 0, 0, 0, 0, 0, 0, 0};                                       \
    if (v_) t_ = *(const f16x8*)(x16 + ((size_t)(imgb + yy_ * Wc + xx_)) * Cc + c2_ * 32 + cg * 8); \
    bD = t_;                                                                   \
} while (0)

    f32x4 acc[2];
    acc[0] = (f32x4){0.f, 0.f, 0.f, 0.f};
    acc[1] = (f32x4){0.f, 0.f, 0.f, 0.f};

    f16x4 aR0, aR1;
    f16x8 bR0, bR1;
    // prologue: phase 0 -> slot0 -> s[0]; phase 1 -> slot1 (held in regs)
    CLOAD(0, aR0, bR0);
    CLOAD(1, aR1, bR1);
    *(f16x4*)&s_a[0][adst] = aR0;
    *(f16x8*)&s_b[0][bdst] = bR0;
    asm volatile("s_waitcnt lgkmcnt(0)" ::: "memory"); SB();
    __builtin_amdgcn_s_barrier(); SB();

#define CBODY(p, aCur, bCur, aNxt, bNxt, bc, bn) do {                          \
    f16x8 af = *(const f16x8*)&s_a[bc][(wm * 16 + (lane & 15)) * 32 + qa];     \
    f16x8 bf0 = *(const f16x8*)&s_b[bc][(wn * 32 + (lane & 15)) * 32 + qa];    \
    f16x8 bf1 = *(const f16x8*)&s_b[bc][(wn * 32 + 16 + (lane & 15)) * 32 + qa];\
    CLOAD((p) + 2, aCur, bCur);                                                \
    acc[0] = __builtin_amdgcn_mfma_f32_16x16x32_f16(af, bf0, acc[0], 0, 0, 0); \
    acc[1] = __builtin_amdgcn_mfma_f32_16x16x32_f16(af, bf1, acc[1], 0, 0, 0); \
    *(f16x4*)&s_a[bn][adst] = aNxt;                                            \
    *(f16x8*)&s_b[bn][bdst] = bNxt;                                            \
    asm volatile("s_waitcnt lgkmcnt(0)" ::: "memory"); SB();                   \
    __builtin_amdgcn_s_barrier(); SB();                                        \
} while (0)

    for (int p = 0; p < 72; p += 2) {
        CBODY(p,     aR0, bR0, aR1, bR1, 0, 1);
        CBODY(p + 1, aR1, bR1, aR0, bR0, 1, 0);
    }

    // epilogue: wm=0 -> taps 0..7 (rows 4g..4g+3), wm=1 -> tap 8 (rows 16,17)
    const int g = lane >> 4;
#pragma unroll
    for (int ni = 0; ni < 2; ++ni) {
        const int p = p0 + wn * 32 + ni * 16 + (lane & 15);
        const int hwq = p - imgb;
        const int hq = hwq / Wc, wq = hwq - hq * Wc;
        if (wm == 0) {
            store_tap(2 * g,     hq, wq, acc[ni][0] + b_off[4 * g],
                                         acc[ni][1] + b_off[4 * g + 1], p, idx4t, wt4t);
            store_tap(2 * g + 1, hq, wq, acc[ni][2] + b_off[4 * g + 2],
                                         acc[ni][3] + b_off[4 * g + 3], p, idx4t, wt4t);
        } else if (g == 0) {
            store_tap(8, hq, wq, acc[ni][0] + b_off[16],
                                 acc[ni][1] + b_off[17], p, idx4t, wt4t);
        }
    }
#undef CLOAD
#undef CBODY
}

// Fused deformable sampling (f16 NHWC gathers) + f16 MFMA GEMM + ReLU.
// Block: 256 threads (4 waves), tile 256 out x 64 pix; wave = 64x64. 576 blocks.
// Weights issued TWO chunks ahead into a 4-deep LDS ring (index ch&3); the
// blend's compiler-inserted corner wait subsumes the weight wait via in-order
// vmcnt retirement (W(t+1) issued before C(t) at chunk t-1). No explicit
// vmcnt asm anywhere; one VMEM wait per chunk covering >=1 full chunk.
__global__ __launch_bounds__(256) void deform_mfma_kernel(
    const f16* __restrict__ x16, const f16* __restrict__ wT2,
    const int4* __restrict__ idx4t, const float4* __restrict__ wt4t,
    f16* __restrict__ o16, float* __restrict__ oN, int last)
{
    __shared__ __align__(16) f16 s_w[4][8192];  // 4 x 16KB ring [o(256)][kk(32)] swz
    __shared__ __align__(16) f16 s_s[2][2048];  // 2 x 4KB  [pix(64)][kk(32)] swz

    const int bid = blockIdx.x;
    const int swz = (bid & 7) * 72 + (bid >> 3); // 576 blocks, XCD-chunked
    const int p0 = swz * 64;
    const int imgb = (p0 / HW) * HW;
    const int tid = threadIdx.x, lane = tid & 63, wid = tid >> 6;
    const int ps = tid >> 2, cg = tid & 3;       // sampling: pixel ps, 8-ch grp cg
    const int qa = ((lane >> 4) ^ ((lane >> 1) & 3)) * 8;
    const int qs = (cg ^ ((ps >> 1) & 3)) * 8;
    const f16* xb = x16 + (size_t)imgb * Cc;

#define ISSUE_W(kt, cw, nb) do {                                               \
    _Pragma("unroll")                                                          \
    for (int i_ = 0; i_ < 4; ++i_) {                                           \
        int u_ = i_ * 256 + tid;                                               \
        int wr_ = u_ >> 2;                                                     \
        int wc_ = ((u_ & 3) ^ ((u_ >> 3) & 3)) * 8;                            \
        const f16* g_ = wT2 + ((size_t)((kt) * 256 + wr_)) * Cc + (cw) * 32 + wc_; \
        __builtin_amdgcn_global_load_lds(                                      \
            (const __attribute__((address_space(1))) void*)g_,                 \
            (__attribute__((address_space(3))) void*)&s_w[nb][u_ * 8], 16, 0, 0); \
    }                                                                          \
} while (0)

// 4 lanes (cg=0..3) of pixel ps read contiguous 64B per corner
#define ISSUE_C(dst, idv, co) do {                                             \
    (dst)[0] = *(const f16x8*)(xb + (size_t)(idv).x * Cc + (co) + cg * 8);     \
    (dst)[1] = *(const f16x8*)(xb + (size_t)(idv).y * Cc + (co) + cg * 8);     \
    (dst)[2] = *(const f16x8*)(xb + (size_t)(idv).z * Cc + (co) + cg * 8);     \
    (dst)[3] = *(const f16x8*)(xb + (size_t)(idv).w * Cc + (co) + cg * 8);     \
} while (0)

#define BLEND_WRITE(src, wvv, nb) do {                                         \
    f16x8 sv_;                                                                 \
    _Pragma("unroll")                                                          \
    for (int j_ = 0; j_ < 8; ++j_) {                                           \
        float s_ = (wvv).x * (float)(src)[0][j_] + (wvv).y * (float)(src)[1][j_]\
                 + (wvv).z * (float)(src)[2][j_] + (wvv).w * (float)(src)[3][j_];\
        sv_[j_] = (f16)s_;                                                     \
    }                                                                          \
    *(f16x8*)&s_s[nb][ps * 32 + qs] = sv_;                                     \
} while (0)

    f32x4 acc[4][4];
#pragma unroll
    for (int mi = 0; mi < 4; ++mi)
#pragma unroll
        for (int ni = 0; ni < 4; ++ni) acc[mi][ni] = (f32x4){0.f, 0.f, 0.f, 0.f};

    f16x8 c4[2][4];
    int4 id = idx4t[p0 + ps];
    float4 wv = wt4t[p0 + ps];
    int4 idN;
    float4 wvN;

    // prologue: W(t=0)->ring0, W(t=1)->ring1; C(chunk0)->blend->s_s[0];
    // C(chunk1) left in flight (blended at chunk 0).
    ISSUE_W(0, 0, 0);
    ISSUE_W(0, 1, 1);
    SB();
    ISSUE_C(c4[1], id, 0);                 // corners for chunk 0
    ISSUE_C(c4[0], id, 32);                // corners for chunk 1
    BLEND_WRITE(c4[1], wv, 0);             // compiler waits W0,W1,C0 (in-order)
    asm volatile("s_waitcnt lgkmcnt(0)" ::: "memory"); SB();
    __builtin_amdgcn_s_barrier(); SB();

    for (int k = 0; k < 9; ++k) {
        const int kn = (k < 8) ? k + 1 : 8;
#pragma unroll
        for (int ch = 0; ch < 8; ++ch) {
            const int bb = ch & 1, nb = bb ^ 1;
            const int wb = ch & 3, wnb = (ch + 2) & 3;
            f16x8 af[4], bf[4];
#pragma unroll
            for (int mi = 0; mi < 4; ++mi)
                af[mi] = *(const f16x8*)&s_w[wb][(wid * 64 + mi * 16 + (lane & 15)) * 32 + qa];
#pragma unroll
            for (int ni = 0; ni < 4; ++ni)
                bf[ni] = *(const f16x8*)&s_s[bb][(ni * 16 + (lane & 15)) * 32 + qa];
            if (ch == 0) {
                idN = idx4t[(size_t)kn * PIX + p0 + ps];
                wvN = wt4t[(size_t)kn * PIX + p0 + ps];
            }
            // weights two chunks ahead (ring), then corners (order pinned by SB)
            ISSUE_W((ch >= 6) ? kn : k, (ch + 2) & 7, wnb);
            SB();
            {
                const int4 idu = (ch >= 6) ? idN : id;
                ISSUE_C(c4[nb], idu, ((ch + 2) & 7) * 32);
            }
            // blend corners for chunk t+1 (issued last chunk; compiler's
            // counted vmcnt here also retires W(t+1) -> ring buffer ready)
            {
                const float4 wvu = (ch == 7) ? wvN : wv;
                BLEND_WRITE(c4[bb], wvu, nb);
            }
            asm volatile("s_waitcnt lgkmcnt(0)" ::: "memory"); SB();
#pragma unroll
            for (int ni = 0; ni < 4; ++ni)
#pragma unroll
                for (int mi = 0; mi < 4; ++mi)
                    acc[mi][ni] = __builtin_amdgcn_mfma_f32_16x16x32_f16(
                        af[mi], bf[ni], acc[mi][ni], 0, 0, 0);
            __builtin_amdgcn_s_barrier(); SB();
        }
        id = idN;
        wv = wvN;
    }

    // epilogue: ReLU; D row = output = (lane>>4)*4+j, col = pixel = lane&15
    if (!last) {
#pragma unroll
        for (int ni = 0; ni < 4; ++ni) {
            const int p = p0 + ni * 16 + (lane & 15);
#pragma unroll
            for (int mi = 0; mi < 4; ++mi) {
                const int o0 = wid * 64 + mi * 16 + (lane >> 4) * 4;
                f32x4 v = acc[mi][ni];
                f16x4 h = {(f16)fmaxf(v[0], 0.f), (f16)fmaxf(v[1], 0.f),
                           (f16)fmaxf(v[2], 0.f), (f16)fmaxf(v[3], 0.f)};
                *(f16x4*)&o16[(size_t)p * Cc + o0] = h;
            }
        }
    } else {
        const int bimg = imgb / HW;
#pragma unroll
        for (int ni = 0; ni < 4; ++ni) {
            const int p = p0 + ni * 16 + (lane & 15);
            const int hwl = p - imgb;
#pragma unroll
            for (int mi = 0; mi < 4; ++mi) {
                const int o0 = wid * 64 + mi * 16 + (lane >> 4) * 4;
#pragma unroll
                for (int j = 0; j < 4; ++j)
                    oN[((size_t)(bimg * Cc + o0 + j)) * HW + hwl] =
                        fmaxf(acc[mi][ni][j], 0.f);
            }
        }
    }
#undef ISSUE_W
#undef ISSUE_C
#undef BLEND_WRITE
}

extern "C" void kernel_launch(void* const* d_in, const int* in_sizes, int n_in,
                              void* d_out, int out_size, void* d_ws, size_t ws_size,
                              hipStream_t stream)
{
    const float* x0 = (const float*)d_in[0];
    float* out = (float*)d_out;

    f16*   x16a = (f16*)d_ws;                          // PIX*Cc f16
    f16*   x16b = x16a + (size_t)PIX * Cc;             // PIX*Cc f16
    f16*   wT2  = x16b + (size_t)PIX * Cc;             // CK*Cc f16
    f16*   woffT = wT2 + (size_t)CK * Cc;              // 9*32*256 f16
    int4*  idx4t = (int4*)(woffT + (size_t)9 * 32 * Cc);
    float4* wt4t = (float4*)(idx4t + (size_t)KK * PIX);

    nhwc_prep_kernel<<<dim3(HW / 64, Cc / 64, Bc), 256, 0, stream>>>(x0, x16a);

    const f16* xin = x16a;
    for (int L = 0; L < 3; ++L) {
        const float* w_off = (const float*)d_in[1 + 3 * L];
        const float* b_off = (const float*)d_in[2 + 3 * L];
        const float* w     = (const float*)d_in[3 + 3 * L];
        const int last = (L == 2);
        f16* xo = (L == 0) ? x16b : x16a;

        transpose_w_kernel<<<(CK * Cc) / 256, 256, 0, stream>>>(w, wT2);
        woff_prep_kernel<<<(9 * 32 * Cc) / 256, 256, 0, stream>>>(w_off, woffT);
        conv_off_mfma_kernel<<<PIX / 64, 256, 0, stream>>>(xin, woffT, b_off, idx4t, wt4t);
        deform_mfma_kernel<<<PIX / 64, 256, 0, stream>>>(
            xin, wT2, idx4t, wt4t, xo, out, last);

        xin = xo;
    }
}